// Round 2
// baseline (3559.908 us; speedup 1.0000x reference)
//
#include <hip/hip_runtime.h>
#include <hip/hip_fp16.h>
#include <math.h>

#define TT 512
#define BB 16
#define EE 100
#define HD 500
#define NEG (-10000.0f)
#define SENT64 0xFFFFFFFFFFFFFFFFull
#define SENT32 0xFFFFFFFFu
#define FTRY 8

typedef __attribute__((ext_vector_type(8))) short short8;
typedef __attribute__((ext_vector_type(4))) float f32x4;
typedef __attribute__((ext_vector_type(4))) unsigned int u32x4;

__device__ inline short f2bf(float f) {
    unsigned u = __builtin_bit_cast(unsigned, f);
    unsigned r = (u + 0x7fffu + ((u >> 16) & 1u)) >> 16;
    return (short)r;
}
__device__ inline unsigned short f2h(float f) {
    __half h = __float2half(f);
    return __builtin_bit_cast(unsigned short, h);
}
__device__ inline float h2f(unsigned short u) {
    __half h = __builtin_bit_cast(__half, u);
    return __half2float(h);
}
__device__ inline float bf2f(unsigned short u) {
    return __builtin_bit_cast(float, ((unsigned)u) << 16);
}

// ---------------- maxlen: 1 + max t with any x[b,t] > 0 ----------------
__global__ void maxlen_kernel(const int* __restrict__ x, int* __restrict__ out) {
    __shared__ int mx;
    int t = threadIdx.x;          // 512 threads
    if (t == 0) mx = 1;
    __syncthreads();
    int any = 0;
    for (int b = 0; b < BB; ++b) any |= (x[b * TT + t] > 0);
    if (any) atomicMax(&mx, t + 1);
    __syncthreads();
    if (t == 0) out[0] = mx;
}

// ---------------- sentinel fill via agent-scope atomic stores (MALL-visible) -------
__global__ void sentfill_kernel(unsigned long long* __restrict__ p, int n) {
    int i = blockIdx.x * 256 + threadIdx.x;
    if (i < n)
        __hip_atomic_store(p + i, SENT64, __ATOMIC_RELAXED, __HIP_MEMORY_SCOPE_AGENT);
}

// ---------------- embedding gather -> bf16 XS (T*B, 128) zero-padded ----------------
__global__ void embed_kernel(const int* __restrict__ x, const float* __restrict__ EW,
                             unsigned short* __restrict__ XS) {
    int idx = blockIdx.x * 256 + threadIdx.x;    // < 8192*128
    int e = idx & 127;
    int r = idx >> 7;          // r = t*16 + b
    int t = r >> 4;
    int b = r & 15;
    unsigned short v = 0;
    if (e < EE) {
        int tok = x[b * TT + t];
        v = (unsigned short)f2bf(EW[(size_t)tok * EE + e]);
    }
    XS[idx] = v;
}

// ---------------- fp32 -> bf16 weight conversion with K padding ----------------
__global__ void wconv_kernel(const float* __restrict__ src, unsigned short* __restrict__ dst,
                             int Ksrc, int Kpad, int total) {
    int i = blockIdx.x * 256 + threadIdx.x;
    if (i >= total) return;
    int r = i / Kpad;
    int k = i - r * Kpad;
    dst[i] = (k < Ksrc) ? (unsigned short)f2bf(src[(size_t)r * Ksrc + k]) : 0;
}

// ---------------- zero the pad columns (1000..1023) of bf16 H0 ----------------
__global__ void padzero_kernel(int* __restrict__ p) {
    int i = blockIdx.x * 256 + threadIdx.x;      // < 8192*12
    if (i >= 8192 * 12) return;
    int r = i / 12, c = i - r * 12;
    p[r * 512 + 500 + c] = 0;                    // shorts 1000..1023 = ints 500..511
}

// ------------- bf16 MFMA GEMM: C[z] = f16(A @ W[z]^T + b1[z] + b2[z]) --------------
// A: (8192, Kpad) bf16. W: (2, 2000, Kpad) bf16. C: (2, 8192, 2000) fp16.
__global__ __launch_bounds__(256) void gemm_mfma(
    const unsigned short* __restrict__ A, const unsigned short* __restrict__ W,
    const float* __restrict__ b1, const float* __restrict__ b2,
    unsigned short* __restrict__ C, int Kpad) {
    __shared__ __align__(16) unsigned short AsS[128 * 40];
    __shared__ __align__(16) unsigned short WsS[64 * 40];
    const int tid = threadIdx.x;
    const int lane = tid & 63;
    const int w = tid >> 6;
    const int quad = lane >> 4;
    const int nl = lane & 15;
    const int bm0 = blockIdx.x * 128;
    const int n0 = blockIdx.y * 64;
    const int z = blockIdx.z;

    const unsigned short* Wz = W + (size_t)z * 2000 * Kpad;
    unsigned short* Cz = C + (size_t)z * 8192 * 2000;
    const float* b1z = b1 + (size_t)z * 2000;
    const float* b2z = b2 + (size_t)z * 2000;

    f32x4 acc[2][4];
#pragma unroll
    for (int mt = 0; mt < 2; ++mt)
#pragma unroll
        for (int nt = 0; nt < 4; ++nt) acc[mt][nt] = (f32x4){0.f, 0.f, 0.f, 0.f};

    const int arow = tid >> 2;
    const int kc = tid & 3;
    const int wn = n0 + arow;

    for (int k0 = 0; k0 < Kpad; k0 += 32) {
        short8 av0 = *(const short8*)(A + (size_t)(bm0 + arow) * Kpad + k0 + kc * 8);
        short8 av1 = *(const short8*)(A + (size_t)(bm0 + 64 + arow) * Kpad + k0 + kc * 8);
        short8 wv = {0, 0, 0, 0, 0, 0, 0, 0};
        if (wn < 2000) wv = *(const short8*)(Wz + (size_t)wn * Kpad + k0 + kc * 8);
        __syncthreads();
        *(short8*)&AsS[arow * 40 + kc * 8] = av0;
        *(short8*)&AsS[(64 + arow) * 40 + kc * 8] = av1;
        *(short8*)&WsS[arow * 40 + kc * 8] = wv;
        __syncthreads();

        short8 af[2], bfr[4];
#pragma unroll
        for (int mt = 0; mt < 2; ++mt)
            af[mt] = *(const short8*)&AsS[(w * 32 + mt * 16 + nl) * 40 + quad * 8];
#pragma unroll
        for (int nt = 0; nt < 4; ++nt)
            bfr[nt] = *(const short8*)&WsS[(nt * 16 + nl) * 40 + quad * 8];
#pragma unroll
        for (int mt = 0; mt < 2; ++mt)
#pragma unroll
            for (int nt = 0; nt < 4; ++nt)
                acc[mt][nt] = __builtin_amdgcn_mfma_f32_16x16x32_bf16(
                    af[mt], bfr[nt], acc[mt][nt], 0, 0, 0);
    }

#pragma unroll
    for (int nt = 0; nt < 4; ++nt) {
        int n = n0 + nt * 16 + nl;
        if (n < 2000) {
            float bb = b1z[n] + b2z[n];
#pragma unroll
            for (int mt = 0; mt < 2; ++mt) {
                int mbase = bm0 + w * 32 + mt * 16 + quad * 4;
#pragma unroll
                for (int reg = 0; reg < 4; ++reg)
                    Cz[(size_t)(mbase + reg) * 2000 + n] = f2h(acc[mt][nt][reg] + bb);
            }
        }
    }
}

// ---------------- persistent-weight recurrence, bf16 MFMA, DATA-IS-FLAG sync -------
// hseq: per dir, (TT+1) write-once buffers of 8192 bf16 in MFMA-A layout, pre-filled
// with 0xFFFF sentinels via agent-scope atomic stores. Producer at step s publishes
// buf[s+1] with 8B agent-scope atomic stores (ALL slots, zeros for k>=HD) -> MALL.
// Consumer stages buf[s] into LDS, retrying any 4B word that still reads 0xFFFFFFFF.
// NEW this round (consumer side only; hang-proof by construction):
//   * adaptive probe: first FTRY retries use sc0-only loads (local XCD L2). If the
//     producer is on the same XCD and sc0sc1 stores update the L2 line en route to
//     MALL, the retry round trip is ~200cy instead of ~900cy. After FTRY failures the
//     loop escalates to the verified sc0 sc1 (MALL) loads -> guaranteed progress.
//   * staleness self-test: when a step needed escalation, re-read one known-good word
//     with sc0. If the fast view STILL shows the sentinel, this wave's L2 holds stale
//     clean lines (cross-XCD placement) -> sticky-escalate = exact baseline behavior.
//   * grid is 128 blocks, dir = bid & 7 (only residues 0/1 work): if HW round-robins
//     blocks across the 8 XCDs by bid%8, each direction's 16 blocks share one XCD.
//     Pure placement hint; correctness never depends on it.
// Stale reads can only return SENT (write-once buffers) -> retry, never wrong data.
__global__ __launch_bounds__(256, 1) void rec10_kernel(
    const unsigned short* __restrict__ G, const float* __restrict__ Whh,
    const int* __restrict__ x, const float* __restrict__ h0,
    const float* __restrict__ c0, int layerbase,
    unsigned short* __restrict__ Hout, unsigned short* __restrict__ hseq,
    const int* __restrict__ mlen)
{
    const int bid = blockIdx.x;
    const int dir = bid & 7;
    if (dir > 1) return;                 // 96 of 128 blocks idle-exit (placement hint)
    const int bsl = bid >> 3;            // 0..15 slice within direction
    const int k0 = bsl * 32;
    const int tid = threadIdx.x;
    const int lane = tid & 63;
    const int w = tid >> 6;          // wave 0..3
    const int quad = lane >> 4;      // 0..3
    const int nl = lane & 15;
    const int L = mlen[0];           // 1..512

    const float* Wd = Whh + (size_t)dir * 2000 * HD;
    const unsigned short* Gd = G + (size_t)dir * TT * BB * 2000;
    unsigned short* hdir = hseq + (size_t)dir * (TT + 1) * 8192;

    __shared__ __align__(16) unsigned short hstage[8192];
    __shared__ float sg[4][32][17];

    // ---- load weights into registers as B fragments (bf16) ----
    short8 bf[2][16];
#pragma unroll
    for (int tl = 0; tl < 2; ++tl) {
        int tt = w * 2 + tl;
        int r = tt * 16 + nl;          // 0..127 local gate row
        int g = r >> 5;                // gate 0..3
        int lkr = r & 31;
        int kk = k0 + lkr;             // output h index
        const float* wrow = (kk < HD) ? (Wd + (size_t)(g * HD + kk) * HD) : (const float*)0;
#pragma unroll
        for (int ks = 0; ks < 16; ++ks) {
            int kg0 = ks * 32 + quad * 8;
            short8 v;
            if (wrow && kg0 + 8 <= HD) {
                float4 f0 = *(const float4*)(wrow + kg0);
                float4 f1 = *(const float4*)(wrow + kg0 + 4);
                v[0] = f2bf(f0.x); v[1] = f2bf(f0.y); v[2] = f2bf(f0.z); v[3] = f2bf(f0.w);
                v[4] = f2bf(f1.x); v[5] = f2bf(f1.y); v[6] = f2bf(f1.z); v[7] = f2bf(f1.w);
            } else {
#pragma unroll
                for (int j = 0; j < 8; ++j) {
                    int kg = kg0 + j;
                    float f = (wrow && kg < HD) ? wrow[kg] : 0.f;
                    v[j] = f2bf(f);
                }
            }
            bf[tl][ks] = v;
        }
    }

    // ---- per-thread persistent state: 2 (b,k) pairs, same k different b ----
    const int lk = tid & 31;
    const int k  = k0 + lk;
    const bool kok = (k < HD);
    const int b0v = tid >> 5;          // 0..7
    const int b1v = 8 + (tid >> 5);    // 8..15
    float h_st[2] = {0.f, 0.f}, c_st[2] = {0.f, 0.f};
    if (kok) {
        size_t base0 = (size_t)(layerbase + dir) * BB * HD + (size_t)b0v * HD + k;
        size_t base1 = (size_t)(layerbase + dir) * BB * HD + (size_t)b1v * HD + k;
        h_st[0] = h0[base0]; c_st[0] = c0[base0];
        h_st[1] = h0[base1]; c_st[1] = c0[base1];
    }

    // ---- publish h0 into buf[0] (ALL slots: zeros for k>=HD; 8B atomic stores) ----
    {
        int i0 = (int)(unsigned short)f2bf(kok ? h_st[0] : 0.f);
        int i1 = (int)(unsigned short)f2bf(kok ? h_st[1] : 0.f);
        int a0 = __shfl_down(i0, 1), c0s = __shfl_down(i0, 2), d0 = __shfl_down(i0, 3);
        int a1 = __shfl_down(i1, 1), c1s = __shfl_down(i1, 2), d1 = __shfl_down(i1, 3);
        if ((lk & 3) == 0) {
            unsigned long long p0 = (unsigned long long)(unsigned)(i0 | (a0 << 16))
                                  | ((unsigned long long)(unsigned)(c0s | (d0 << 16)) << 32);
            unsigned long long p1 = (unsigned long long)(unsigned)(i1 | (a1 << 16))
                                  | ((unsigned long long)(unsigned)(c1s | (d1 << 16)) << 32);
            int idx0 = bsl * 512 + (b0v + 16 * (lk >> 3)) * 8 + (lk & 7);
            int idx1 = bsl * 512 + (b1v + 16 * (lk >> 3)) * 8 + (lk & 7);
            __hip_atomic_store((unsigned long long*)(hdir + idx0), p0,
                               __ATOMIC_RELAXED, __HIP_MEMORY_SCOPE_AGENT);
            __hip_atomic_store((unsigned long long*)(hdir + idx1), p1,
                               __ATOMIC_RELAXED, __HIP_MEMORY_SCOPE_AGENT);
        }
    }

    // ---- prefetch step-0 G (raw) + mask ----
    unsigned short gpraw[2][4]; int m[2];
    m[0] = m[1] = 0;
    gpraw[0][0]=gpraw[0][1]=gpraw[0][2]=gpraw[0][3]=0;
    gpraw[1][0]=gpraw[1][1]=gpraw[1][2]=gpraw[1][3]=0;
    {
        int t = dir ? (L - 1) : 0;
        if (kok) {
            const unsigned short* gr0 = Gd + ((size_t)t * BB + b0v) * 2000 + k;
            const unsigned short* gr1 = Gd + ((size_t)t * BB + b1v) * 2000 + k;
            gpraw[0][0] = gr0[0]; gpraw[0][1] = gr0[HD]; gpraw[0][2] = gr0[2 * HD]; gpraw[0][3] = gr0[3 * HD];
            gpraw[1][0] = gr1[0]; gpraw[1][1] = gr1[HD]; gpraw[1][2] = gr1[2 * HD]; gpraw[1][3] = gr1[3 * HD];
            m[0] = x[b0v * TT + t] > 0;
            m[1] = x[b1v * TT + t] > 0;
        }
    }

    int slowmode = 0;   // wave-uniform sticky escalation flag

    for (int s = 0; s < L; ++s) {
        const int t = dir ? (L - 1 - s) : s;
        const unsigned short* bufr = hdir + (size_t)s * 8192;
        unsigned short* bufw = hdir + (size_t)(s + 1) * 8192;

        // ---- poll-stage buf[s] into LDS: per-thread 4x16B loads, retry until no
        //      4B word is the sentinel. Adaptive: sc0 (L2) probes, escalate to
        //      sc0 sc1 (MALL) after FTRY failures; sticky on proven-stale L2. ----
        {
            const unsigned short* p0 = bufr + (tid +   0) * 8;
            const unsigned short* p1 = bufr + (tid + 256) * 8;
            const unsigned short* p2 = bufr + (tid + 512) * 8;
            const unsigned short* p3 = bufr + (tid + 768) * 8;
            u32x4 c0v, c1v, c2v, c3v;
            int tries = 0;
            for (;;) {
                if (!slowmode && tries < FTRY) {
                    asm volatile(
                        "global_load_dwordx4 %0, %4, off sc0\n\t"
                        "global_load_dwordx4 %1, %5, off sc0\n\t"
                        "global_load_dwordx4 %2, %6, off sc0\n\t"
                        "global_load_dwordx4 %3, %7, off sc0\n\t"
                        "s_waitcnt vmcnt(0)"
                        : "=&v"(c0v), "=&v"(c1v), "=&v"(c2v), "=&v"(c3v)
                        : "v"(p0), "v"(p1), "v"(p2), "v"(p3)
                        : "memory");
                } else {
                    asm volatile(
                        "global_load_dwordx4 %0, %4, off sc0 sc1\n\t"
                        "global_load_dwordx4 %1, %5, off sc0 sc1\n\t"
                        "global_load_dwordx4 %2, %6, off sc0 sc1\n\t"
                        "global_load_dwordx4 %3, %7, off sc0 sc1\n\t"
                        "s_waitcnt vmcnt(0)"
                        : "=&v"(c0v), "=&v"(c1v), "=&v"(c2v), "=&v"(c3v)
                        : "v"(p0), "v"(p1), "v"(p2), "v"(p3)
                        : "memory");
                }
                unsigned bad = 0;
#pragma unroll
                for (int q = 0; q < 4; ++q)
                    bad |= (c0v[q] == SENT32) | (c1v[q] == SENT32)
                         | (c2v[q] == SENT32) | (c3v[q] == SENT32);
                if (!bad) break;
                ++tries;
            }
            // staleness self-test: this step needed escalation -> re-read a word we
            // KNOW holds data via the fast path. Sentinel => stale clean L2 line =>
            // fast probes can never work for this wave; sticky-escalate (= baseline).
            if (!slowmode && tries >= FTRY) {
                u32x4 tv;
                asm volatile(
                    "global_load_dwordx4 %0, %1, off sc0\n\t"
                    "s_waitcnt vmcnt(0)"
                    : "=&v"(tv) : "v"(p0) : "memory");
                if (__any(tv[0] == SENT32)) slowmode = 1;
            }
            *(u32x4*)&hstage[(tid +   0) * 8] = c0v;
            *(u32x4*)&hstage[(tid + 256) * 8] = c1v;
            *(u32x4*)&hstage[(tid + 512) * 8] = c2v;
            *(u32x4*)&hstage[(tid + 768) * 8] = c3v;
        }
        __syncthreads();

        // ---- recurrent preactivation via MFMA (A fragments from LDS) ----
        f32x4 acc0 = {0.f, 0.f, 0.f, 0.f};
        f32x4 acc1 = {0.f, 0.f, 0.f, 0.f};
#pragma unroll
        for (int ks = 0; ks < 16; ++ks) {
            short8 a = *(const short8*)&hstage[ks * 512 + lane * 8];
            acc0 = __builtin_amdgcn_mfma_f32_16x16x32_bf16(a, bf[0][ks], acc0, 0, 0, 0);
            acc1 = __builtin_amdgcn_mfma_f32_16x16x32_bf16(a, bf[1][ks], acc1, 0, 0, 0);
        }

        // ---- scatter D to LDS: sg[gate][lk][b] ----
        {
            int r0 = (w * 2 + 0) * 16 + nl;
            int r1 = (w * 2 + 1) * 16 + nl;
            int g0r = r0 >> 5, lk0 = r0 & 31;
            int g1r = r1 >> 5, lk1 = r1 & 31;
#pragma unroll
            for (int reg = 0; reg < 4; ++reg) {
                int b = quad * 4 + reg;
                sg[g0r][lk0][b] = acc0[reg];
                sg[g1r][lk1][b] = acc1[reg];
            }
        }
        __syncthreads();

        // ---- epilogue: gates + state update (identical math to verified baseline),
        //      then publish ASAP, then Hout (off the peers' critical path) ----
        int i0 = 0, i1 = 0;
        if (kok) {
#pragma unroll
            for (int p = 0; p < 2; ++p) {
                int b = p ? b1v : b0v;
                float si  = sg[0][lk][b] + h2f(gpraw[p][0]);
                float sf  = sg[1][lk][b] + h2f(gpraw[p][1]);
                float sgg = sg[2][lk][b] + h2f(gpraw[p][2]);
                float so  = sg[3][lk][b] + h2f(gpraw[p][3]);
                float ig = 1.f / (1.f + __expf(-si));
                float fg = 1.f / (1.f + __expf(-sf));
                float gg = tanhf(sgg);
                float og = 1.f / (1.f + __expf(-so));
                float c_new = fg * c_st[p] + ig * gg;
                float h_new = og * tanhf(c_new);
                float hn = m[p] ? h_new : h_st[p];
                float cn = m[p] ? c_new : c_st[p];
                h_st[p] = hn; c_st[p] = cn;
            }
            i0 = (int)(unsigned short)f2bf(h_st[0]);
            i1 = (int)(unsigned short)f2bf(h_st[1]);
        }

        // ---- publish h into buf[s+1] (ALL slots; 8B atomic stores; no barrier) ----
        {
            int a0 = __shfl_down(i0, 1), c0s = __shfl_down(i0, 2), d0 = __shfl_down(i0, 3);
            int a1 = __shfl_down(i1, 1), c1s = __shfl_down(i1, 2), d1 = __shfl_down(i1, 3);
            if ((lk & 3) == 0) {
                unsigned long long p0 = (unsigned long long)(unsigned)(i0 | (a0 << 16))
                                      | ((unsigned long long)(unsigned)(c0s | (d0 << 16)) << 32);
                unsigned long long p1 = (unsigned long long)(unsigned)(i1 | (a1 << 16))
                                      | ((unsigned long long)(unsigned)(c1s | (d1 << 16)) << 32);
                int idx0 = bsl * 512 + (b0v + 16 * (lk >> 3)) * 8 + (lk & 7);
                int idx1 = bsl * 512 + (b1v + 16 * (lk >> 3)) * 8 + (lk & 7);
                __hip_atomic_store((unsigned long long*)(bufw + idx0), p0,
                                   __ATOMIC_RELAXED, __HIP_MEMORY_SCOPE_AGENT);
                __hip_atomic_store((unsigned long long*)(bufw + idx1), p1,
                                   __ATOMIC_RELAXED, __HIP_MEMORY_SCOPE_AGENT);
            }
        }

        // ---- Hout (bf16, stride 1024): same bits as published; after publish ----
        if (kok) {
            Hout[((size_t)t * BB + b0v) * 1024 + dir * HD + k] =
                (unsigned short)(m[0] ? i0 : 0);
            Hout[((size_t)t * BB + b1v) * 1024 + dir * HD + k] =
                (unsigned short)(m[1] ? i1 : 0);
        }

        // ---- prefetch next step's G (raw) + mask: overlaps next poll-stage ----
        if (s + 1 < L) {
            int tn = dir ? (L - 2 - s) : (s + 1);
            if (kok) {
                const unsigned short* gr0 = Gd + ((size_t)tn * BB + b0v) * 2000 + k;
                const unsigned short* gr1 = Gd + ((size_t)tn * BB + b1v) * 2000 + k;
                gpraw[0][0] = gr0[0]; gpraw[0][1] = gr0[HD]; gpraw[0][2] = gr0[2 * HD]; gpraw[0][3] = gr0[3 * HD];
                gpraw[1][0] = gr1[0]; gpraw[1][1] = gr1[HD]; gpraw[1][2] = gr1[2 * HD]; gpraw[1][3] = gr1[3 * HD];
                m[0] = x[b0v * TT + tn] > 0;
                m[1] = x[b1v * TT + tn] > 0;
            }
        }
    }
}

// -------- output projection: Y (T,B,32) = bf16HS @ Wo^T + bo, masked ----------------
__global__ void outproj_kernel(const unsigned short* __restrict__ HS,
                               const float* __restrict__ Wo,
                               const float* __restrict__ bo, const int* __restrict__ x,
                               float* __restrict__ Y) {
    int idx = blockIdx.x * 256 + threadIdx.x;
    int r = idx >> 5;
    int n = idx & 31;
    int t = r >> 4;
    int b = r & 15;
    float out = 0.f;
    if (x[b * TT + t] > 0) {
        const unsigned short* h = HS + (size_t)r * 1024;
        const float* wrow = Wo + (size_t)n * 1000;
        float s = 0.f;
#pragma unroll 4
        for (int q = 0; q < 1000; q += 8) {
            short8 hv = *(const short8*)(h + q);
            float4 w0 = *(const float4*)(wrow + q);
            float4 w1 = *(const float4*)(wrow + q + 4);
            s += bf2f((unsigned short)hv[0]) * w0.x + bf2f((unsigned short)hv[1]) * w0.y
               + bf2f((unsigned short)hv[2]) * w0.z + bf2f((unsigned short)hv[3]) * w0.w
               + bf2f((unsigned short)hv[4]) * w1.x + bf2f((unsigned short)hv[5]) * w1.y
               + bf2f((unsigned short)hv[6]) * w1.z + bf2f((unsigned short)hv[7]) * w1.w;
        }
        out = s + bo[n];
    }
    Y[idx] = out;
}

// ---------------- CRF: gold score + forward scan ----------------
__global__ __launch_bounds__(1024) void crf_kernel(
    const float* __restrict__ Y, const int* __restrict__ x, const int* __restrict__ y0,
    const float* __restrict__ trans, float* __restrict__ out_pb) {
    int b = blockIdx.x;
    int tid = threadIdx.x;
    int i = tid >> 5;
    int j = tid & 31;
    float tr_ij = trans[i * 32 + j];

    __shared__ float sc[32];
    __shared__ float wred[16];
    __shared__ float goldS;

    float gp = 0.f;
    if (tid < TT) {
        int t = tid;
        int xm = x[b * TT + t];
        float mf = (xm > 0) ? 1.f : 0.f;
        int ynext = y0[b * TT + t];
        int yprev = (t == 0) ? 1 : y0[b * TT + t - 1];
        gp = Y[((size_t)t * BB + b) * 32 + ynext] + trans[ynext * 32 + yprev] * mf;
    }
#pragma unroll
    for (int d = 32; d >= 1; d >>= 1) gp += __shfl_down(gp, d);
    if ((tid & 63) == 0) wred[tid >> 6] = gp;
    __syncthreads();
    if (tid == 0) {
        float s = 0.f;
        for (int ww = 0; ww < 16; ++ww) s += wred[ww];
        goldS = s;
    }
    if (tid < 32) sc[tid] = (tid == 1) ? 0.f : NEG;
    __syncthreads();

    for (int t = 0; t < TT; ++t) {
        float sj = sc[j];
        float z = sj + tr_ij;
        float mx = z;
#pragma unroll
        for (int d = 16; d >= 1; d >>= 1) mx = fmaxf(mx, __shfl_xor(mx, d));
        float e = __expf(z - mx);
#pragma unroll
        for (int d = 16; d >= 1; d >>= 1) e += __shfl_xor(e, d);
        float cm = sj;
#pragma unroll
        for (int d = 16; d >= 1; d >>= 1) cm = fmaxf(cm, __shfl_xor(cm, d));
        float emit_i = Y[((size_t)t * BB + b) * 32 + i];
        float newv = emit_i + mx + __logf(e);
        int mm = x[b * TT + t] > 0;
        __syncthreads();
        if (j == 0) sc[i] = mm ? newv : cm;
        __syncthreads();
    }

    if (tid < 32) {
        float v = sc[tid];
        float mx = v;
#pragma unroll
        for (int d = 16; d >= 1; d >>= 1) mx = fmaxf(mx, __shfl_xor(mx, d));
        float e = __expf(v - mx);
#pragma unroll
        for (int d = 16; d >= 1; d >>= 1) e += __shfl_xor(e, d);
        if (tid == 0) out_pb[b] = (mx + __logf(e)) - goldS;
    }
}

__global__ void final_kernel(const float* __restrict__ out_pb, float* __restrict__ out) {
    if (threadIdx.x == 0 && blockIdx.x == 0) {
        float s = 0.f;
        for (int b = 0; b < BB; ++b) s += out_pb[b];
        out[0] = s / (float)BB;
    }
}

extern "C" void kernel_launch(void* const* d_in, const int* in_sizes, int n_in,
                              void* d_out, int out_size, void* d_ws, size_t ws_size,
                              hipStream_t stream) {
    const int*   x     = (const int*)d_in[0];
    const int*   y0    = (const int*)d_in[1];
    const float* EW    = (const float*)d_in[2];
    const float* Wih0  = (const float*)d_in[3];
    const float* Whh0  = (const float*)d_in[4];
    const float* bih0  = (const float*)d_in[5];
    const float* bhh0  = (const float*)d_in[6];
    const float* Wih1  = (const float*)d_in[7];
    const float* Whh1  = (const float*)d_in[8];
    const float* bih1  = (const float*)d_in[9];
    const float* bhh1  = (const float*)d_in[10];
    const float* Wo    = (const float*)d_in[11];
    const float* bo    = (const float*)d_in[12];
    const float* trans = (const float*)d_in[13];
    const float* h0    = (const float*)d_in[14];
    const float* c0    = (const float*)d_in[15];

    float* ws = (float*)d_ws;
    // Layout (float offsets), total 31,803,393 floats = 127.2 MB (< R3-proven 134 MB):
    //   [0, 524288)            XS bf16 (8192x128); Y fp32(262144)+crfbuf alias
    //   [524288, 16908288)     Gh: fp16 (2, 8192, 2000)
    //   [16908288, 21102592)   H0 bf16 (8192 x 1024)
    //   [21102592, 25296896)   HS bf16 (8192 x 1024)
    //   [25296896, 25552896)   Wb0 bf16 (2,2000,128)
    //   [25552896, 27600896)   Wb1 bf16 (2,2000,1024)
    //   [27600896, 31803392)   hseq: 2 dirs x 513 x 8192 bf16 (shared by both layers)
    //   [31803392]             mlen (1 int)
    unsigned short* XS = (unsigned short*)ws;
    float* Y      = ws;
    float* crfbuf = ws + 262144;
    unsigned short* Gh   = (unsigned short*)(ws + 524288);
    unsigned short* H0b  = (unsigned short*)(ws + 16908288);
    unsigned short* HSb  = (unsigned short*)(ws + 21102592);
    unsigned short* Wb0  = (unsigned short*)(ws + 25296896);
    unsigned short* Wb1  = (unsigned short*)(ws + 25552896);
    unsigned short* hseq = (unsigned short*)(ws + 27600896);
    int* mlen     = (int*)(ws + 31803392);
    const int nsent64 = 2 * (TT + 1) * 8192 / 4;   // 2,101,248 u64 words

    // Phase 0: maxlen + sentinel fill #1
    maxlen_kernel<<<1, 512, 0, stream>>>(x, mlen);
    sentfill_kernel<<<(nsent64 + 255) / 256, 256, 0, stream>>>((unsigned long long*)hseq, nsent64);

    // Phase 1: embedding -> bf16 XS (padded K=128); weight conversions
    embed_kernel<<<4096, 256, 0, stream>>>(x, EW, XS);
    wconv_kernel<<<(512000 + 255) / 256, 256, 0, stream>>>(Wih0, Wb0, 100, 128, 512000);
    wconv_kernel<<<(4096000 + 255) / 256, 256, 0, stream>>>(Wih1, Wb1, 1000, 1024, 4096000);

    // Phase 2: layer-0 input projections (MFMA, Kpad=128) -> fp16 Gh; zero H0 pads
    gemm_mfma<<<dim3(64, 32, 2), 256, 0, stream>>>(XS, Wb0, bih0, bhh0, Gh, 128);
    padzero_kernel<<<(98304 + 255) / 256, 256, 0, stream>>>((int*)H0b);

    // Phase 3: layer-0 recurrence -> bf16 H0 (adaptive L2 probe; 128 blocks so the
    //          16 active blocks per dir co-locate on one XCD if bid%8 placement holds)
    rec10_kernel<<<128, 256, 0, stream>>>(Gh, Whh0, x, h0, c0, 0, H0b, hseq, mlen);

    // Phase 4: layer-1 input projections (MFMA, Kpad=1024) -> fp16 Gh; refill hseq
    gemm_mfma<<<dim3(64, 32, 2), 256, 0, stream>>>(H0b, Wb1, bih1, bhh1, Gh, 1024);
    sentfill_kernel<<<(nsent64 + 255) / 256, 256, 0, stream>>>((unsigned long long*)hseq, nsent64);

    // Phase 5: layer-1 recurrence -> bf16 HS
    rec10_kernel<<<128, 256, 0, stream>>>(Gh, Whh1, x, h0, c0, 2, HSb, hseq, mlen);

    // Phase 6: output projection (masked; bf16 HS, stride 1024)
    outproj_kernel<<<1024, 256, 0, stream>>>(HSb, Wo, bo, x, Y);

    // Phase 7: CRF gold + forward scan
    crf_kernel<<<BB, 1024, 0, stream>>>(Y, x, y0, trans, crfbuf);

    // Phase 8: mean
    final_kernel<<<1, 64, 0, stream>>>(crfbuf, (float*)d_out);
}

// Round 3
// 3320.765 us; speedup vs baseline: 1.0720x; 1.0720x over previous
//
#include <hip/hip_runtime.h>
#include <hip/hip_fp16.h>
#include <math.h>

#define TT 512
#define BB 16
#define EE 100
#define HD 500
#define NEG (-10000.0f)
#define SENT64 0xFFFFFFFFFFFFFFFFull
#define SENT32 0xFFFFFFFFu

typedef __attribute__((ext_vector_type(8))) short short8;
typedef __attribute__((ext_vector_type(4))) float f32x4;
typedef __attribute__((ext_vector_type(4))) unsigned int u32x4;

__device__ inline short f2bf(float f) {
    unsigned u = __builtin_bit_cast(unsigned, f);
    unsigned r = (u + 0x7fffu + ((u >> 16) & 1u)) >> 16;
    return (short)r;
}
__device__ inline unsigned short f2h(float f) {
    __half h = __float2half(f);
    return __builtin_bit_cast(unsigned short, h);
}
__device__ inline float h2f(unsigned short u) {
    __half h = __builtin_bit_cast(__half, u);
    return __half2float(h);
}
__device__ inline float bf2f(unsigned short u) {
    return __builtin_bit_cast(float, ((unsigned)u) << 16);
}

// ---------------- maxlen: 1 + max t with any x[b,t] > 0 ----------------
__global__ void maxlen_kernel(const int* __restrict__ x, int* __restrict__ out) {
    __shared__ int mx;
    int t = threadIdx.x;          // 512 threads
    if (t == 0) mx = 1;
    __syncthreads();
    int any = 0;
    for (int b = 0; b < BB; ++b) any |= (x[b * TT + t] > 0);
    if (any) atomicMax(&mx, t + 1);
    __syncthreads();
    if (t == 0) out[0] = mx;
}

// ---------------- sentinel fill via agent-scope atomic stores (MALL-visible) -------
__global__ void sentfill_kernel(unsigned long long* __restrict__ p, int n) {
    int i = blockIdx.x * 256 + threadIdx.x;
    if (i < n)
        __hip_atomic_store(p + i, SENT64, __ATOMIC_RELAXED, __HIP_MEMORY_SCOPE_AGENT);
}

// ---------------- embedding gather -> bf16 XS (T*B, 128) zero-padded ----------------
__global__ void embed_kernel(const int* __restrict__ x, const float* __restrict__ EW,
                             unsigned short* __restrict__ XS) {
    int idx = blockIdx.x * 256 + threadIdx.x;    // < 8192*128
    int e = idx & 127;
    int r = idx >> 7;          // r = t*16 + b
    int t = r >> 4;
    int b = r & 15;
    unsigned short v = 0;
    if (e < EE) {
        int tok = x[b * TT + t];
        v = (unsigned short)f2bf(EW[(size_t)tok * EE + e]);
    }
    XS[idx] = v;
}

// ---------------- fp32 -> bf16 weight conversion with K padding ----------------
__global__ void wconv_kernel(const float* __restrict__ src, unsigned short* __restrict__ dst,
                             int Ksrc, int Kpad, int total) {
    int i = blockIdx.x * 256 + threadIdx.x;
    if (i >= total) return;
    int r = i / Kpad;
    int k = i - r * Kpad;
    dst[i] = (k < Ksrc) ? (unsigned short)f2bf(src[(size_t)r * Ksrc + k]) : 0;
}

// ---------------- zero the pad columns (1000..1023) of bf16 H0 ----------------
__global__ void padzero_kernel(int* __restrict__ p) {
    int i = blockIdx.x * 256 + threadIdx.x;      // < 8192*12
    if (i >= 8192 * 12) return;
    int r = i / 12, c = i - r * 12;
    p[r * 512 + 500 + c] = 0;                    // shorts 1000..1023 = ints 500..511
}

// ------------- bf16 MFMA GEMM: C[z] = f16(A @ W[z]^T + b1[z] + b2[z]) --------------
// A: (8192, Kpad) bf16. W: (2, 2000, Kpad) bf16. C: (2, 8192, 2000) fp16.
__global__ __launch_bounds__(256) void gemm_mfma(
    const unsigned short* __restrict__ A, const unsigned short* __restrict__ W,
    const float* __restrict__ b1, const float* __restrict__ b2,
    unsigned short* __restrict__ C, int Kpad) {
    __shared__ __align__(16) unsigned short AsS[128 * 40];
    __shared__ __align__(16) unsigned short WsS[64 * 40];
    const int tid = threadIdx.x;
    const int lane = tid & 63;
    const int w = tid >> 6;
    const int quad = lane >> 4;
    const int nl = lane & 15;
    const int bm0 = blockIdx.x * 128;
    const int n0 = blockIdx.y * 64;
    const int z = blockIdx.z;

    const unsigned short* Wz = W + (size_t)z * 2000 * Kpad;
    unsigned short* Cz = C + (size_t)z * 8192 * 2000;
    const float* b1z = b1 + (size_t)z * 2000;
    const float* b2z = b2 + (size_t)z * 2000;

    f32x4 acc[2][4];
#pragma unroll
    for (int mt = 0; mt < 2; ++mt)
#pragma unroll
        for (int nt = 0; nt < 4; ++nt) acc[mt][nt] = (f32x4){0.f, 0.f, 0.f, 0.f};

    const int arow = tid >> 2;
    const int kc = tid & 3;
    const int wn = n0 + arow;

    for (int k0 = 0; k0 < Kpad; k0 += 32) {
        short8 av0 = *(const short8*)(A + (size_t)(bm0 + arow) * Kpad + k0 + kc * 8);
        short8 av1 = *(const short8*)(A + (size_t)(bm0 + 64 + arow) * Kpad + k0 + kc * 8);
        short8 wv = {0, 0, 0, 0, 0, 0, 0, 0};
        if (wn < 2000) wv = *(const short8*)(Wz + (size_t)wn * Kpad + k0 + kc * 8);
        __syncthreads();
        *(short8*)&AsS[arow * 40 + kc * 8] = av0;
        *(short8*)&AsS[(64 + arow) * 40 + kc * 8] = av1;
        *(short8*)&WsS[arow * 40 + kc * 8] = wv;
        __syncthreads();

        short8 af[2], bfr[4];
#pragma unroll
        for (int mt = 0; mt < 2; ++mt)
            af[mt] = *(const short8*)&AsS[(w * 32 + mt * 16 + nl) * 40 + quad * 8];
#pragma unroll
        for (int nt = 0; nt < 4; ++nt)
            bfr[nt] = *(const short8*)&WsS[(nt * 16 + nl) * 40 + quad * 8];
#pragma unroll
        for (int mt = 0; mt < 2; ++mt)
#pragma unroll
            for (int nt = 0; nt < 4; ++nt)
                acc[mt][nt] = __builtin_amdgcn_mfma_f32_16x16x32_bf16(
                    af[mt], bfr[nt], acc[mt][nt], 0, 0, 0);
    }

#pragma unroll
    for (int nt = 0; nt < 4; ++nt) {
        int n = n0 + nt * 16 + nl;
        if (n < 2000) {
            float bb = b1z[n] + b2z[n];
#pragma unroll
            for (int mt = 0; mt < 2; ++mt) {
                int mbase = bm0 + w * 32 + mt * 16 + quad * 4;
#pragma unroll
                for (int reg = 0; reg < 4; ++reg)
                    Cz[(size_t)(mbase + reg) * 2000 + n] = f2h(acc[mt][nt][reg] + bb);
            }
        }
    }
}

// ---------------- persistent-weight recurrence, bf16 MFMA, DATA-IS-FLAG sync -------
// hseq: per dir, (TT+1) write-once buffers of 8192 bf16 in MFMA-A layout, pre-filled
// with 0xFFFF sentinels via agent-scope atomic stores. Producer at step s publishes
// buf[s+1] with 8B agent-scope atomic stores (ALL slots, zeros for k>=HD) -> MALL.
// Consumer stages buf[s] into LDS with sc0 sc1 dwordx4 loads, retrying any 4B word
// that still reads 0xFFFFFFFF (two bf16 NaNs - unreachable from f2bf of finite h).
// NEW this round: STAGGERED DOUBLE-SET POLLING. Two load sets (same addresses) kept
// in flight, alternately completed via counted s_waitcnt vmcnt(4) -> MALL is sampled
// every ~half a load round trip, halving the discovery quantum. Register safety: each
// counted wait is an asm with the guarded set as "+v" in-outs (compiler cannot hoist
// the sentinel check above the wait or recycle in-flight regs - ERRATA#18 discipline).
// Always re-issues on failure -> hang-free. Stale reads can only return SENT
// (write-once buffers) -> retry, never wrong data. No fences, no barriers.
__global__ __launch_bounds__(256, 1) void rec10_kernel(
    const unsigned short* __restrict__ G, const float* __restrict__ Whh,
    const int* __restrict__ x, const float* __restrict__ h0,
    const float* __restrict__ c0, int layerbase,
    unsigned short* __restrict__ Hout, unsigned short* __restrict__ hseq,
    const int* __restrict__ mlen)
{
    const int blk = blockIdx.x;
    const int dir = blk >> 4;
    const int bsl = blk & 15;
    const int k0 = bsl * 32;
    const int tid = threadIdx.x;
    const int lane = tid & 63;
    const int w = tid >> 6;          // wave 0..3
    const int quad = lane >> 4;      // 0..3
    const int nl = lane & 15;
    const int L = mlen[0];           // 1..512

    const float* Wd = Whh + (size_t)dir * 2000 * HD;
    const unsigned short* Gd = G + (size_t)dir * TT * BB * 2000;
    unsigned short* hdir = hseq + (size_t)dir * (TT + 1) * 8192;

    __shared__ __align__(16) unsigned short hstage[8192];
    __shared__ float sg[4][32][17];

    // ---- load weights into registers as B fragments (bf16) ----
    short8 bf[2][16];
#pragma unroll
    for (int tl = 0; tl < 2; ++tl) {
        int tt = w * 2 + tl;
        int r = tt * 16 + nl;          // 0..127 local gate row
        int g = r >> 5;                // gate 0..3
        int lkr = r & 31;
        int kk = k0 + lkr;             // output h index
        const float* wrow = (kk < HD) ? (Wd + (size_t)(g * HD + kk) * HD) : (const float*)0;
#pragma unroll
        for (int ks = 0; ks < 16; ++ks) {
            int kg0 = ks * 32 + quad * 8;
            short8 v;
            if (wrow && kg0 + 8 <= HD) {
                float4 f0 = *(const float4*)(wrow + kg0);
                float4 f1 = *(const float4*)(wrow + kg0 + 4);
                v[0] = f2bf(f0.x); v[1] = f2bf(f0.y); v[2] = f2bf(f0.z); v[3] = f2bf(f0.w);
                v[4] = f2bf(f1.x); v[5] = f2bf(f1.y); v[6] = f2bf(f1.z); v[7] = f2bf(f1.w);
            } else {
#pragma unroll
                for (int j = 0; j < 8; ++j) {
                    int kg = kg0 + j;
                    float f = (wrow && kg < HD) ? wrow[kg] : 0.f;
                    v[j] = f2bf(f);
                }
            }
            bf[tl][ks] = v;
        }
    }

    // ---- per-thread persistent state: 2 (b,k) pairs, same k different b ----
    const int lk = tid & 31;
    const int k  = k0 + lk;
    const bool kok = (k < HD);
    const int b0v = tid >> 5;          // 0..7
    const int b1v = 8 + (tid >> 5);    // 8..15
    float h_st[2] = {0.f, 0.f}, c_st[2] = {0.f, 0.f};
    if (kok) {
        size_t base0 = (size_t)(layerbase + dir) * BB * HD + (size_t)b0v * HD + k;
        size_t base1 = (size_t)(layerbase + dir) * BB * HD + (size_t)b1v * HD + k;
        h_st[0] = h0[base0]; c_st[0] = c0[base0];
        h_st[1] = h0[base1]; c_st[1] = c0[base1];
    }

    // ---- publish h0 into buf[0] (ALL slots: zeros for k>=HD; 8B atomic stores) ----
    {
        int i0 = (int)(unsigned short)f2bf(kok ? h_st[0] : 0.f);
        int i1 = (int)(unsigned short)f2bf(kok ? h_st[1] : 0.f);
        int a0 = __shfl_down(i0, 1), c0s = __shfl_down(i0, 2), d0 = __shfl_down(i0, 3);
        int a1 = __shfl_down(i1, 1), c1s = __shfl_down(i1, 2), d1 = __shfl_down(i1, 3);
        if ((lk & 3) == 0) {
            unsigned long long p0 = (unsigned long long)(unsigned)(i0 | (a0 << 16))
                                  | ((unsigned long long)(unsigned)(c0s | (d0 << 16)) << 32);
            unsigned long long p1 = (unsigned long long)(unsigned)(i1 | (a1 << 16))
                                  | ((unsigned long long)(unsigned)(c1s | (d1 << 16)) << 32);
            int idx0 = bsl * 512 + (b0v + 16 * (lk >> 3)) * 8 + (lk & 7);
            int idx1 = bsl * 512 + (b1v + 16 * (lk >> 3)) * 8 + (lk & 7);
            __hip_atomic_store((unsigned long long*)(hdir + idx0), p0,
                               __ATOMIC_RELAXED, __HIP_MEMORY_SCOPE_AGENT);
            __hip_atomic_store((unsigned long long*)(hdir + idx1), p1,
                               __ATOMIC_RELAXED, __HIP_MEMORY_SCOPE_AGENT);
        }
    }

    // ---- prefetch step-0 G (raw) + mask ----
    unsigned short gpraw[2][4]; int m[2];
    m[0] = m[1] = 0;
    gpraw[0][0]=gpraw[0][1]=gpraw[0][2]=gpraw[0][3]=0;
    gpraw[1][0]=gpraw[1][1]=gpraw[1][2]=gpraw[1][3]=0;
    {
        int t = dir ? (L - 1) : 0;
        if (kok) {
            const unsigned short* gr0 = Gd + ((size_t)t * BB + b0v) * 2000 + k;
            const unsigned short* gr1 = Gd + ((size_t)t * BB + b1v) * 2000 + k;
            gpraw[0][0] = gr0[0]; gpraw[0][1] = gr0[HD]; gpraw[0][2] = gr0[2 * HD]; gpraw[0][3] = gr0[3 * HD];
            gpraw[1][0] = gr1[0]; gpraw[1][1] = gr1[HD]; gpraw[1][2] = gr1[2 * HD]; gpraw[1][3] = gr1[3 * HD];
            m[0] = x[b0v * TT + t] > 0;
            m[1] = x[b1v * TT + t] > 0;
        }
    }

    for (int s = 0; s < L; ++s) {
        const int t = dir ? (L - 1 - s) : s;
        const unsigned short* bufr = hdir + (size_t)s * 8192;
        unsigned short* bufw = hdir + (size_t)(s + 1) * 8192;

        // ---- poll-stage buf[s] into LDS: staggered double-set sentinel polling ----
        {
            const unsigned short* p0 = bufr + (tid +   0) * 8;
            const unsigned short* p1 = bufr + (tid + 256) * 8;
            const unsigned short* p2 = bufr + (tid + 512) * 8;
            const unsigned short* p3 = bufr + (tid + 768) * 8;
            u32x4 a0v, a1v, a2v, a3v, b0q, b1q, b2q, b3q;
            // prime set A
            asm volatile(
                "global_load_dwordx4 %0, %4, off sc0 sc1\n\t"
                "global_load_dwordx4 %1, %5, off sc0 sc1\n\t"
                "global_load_dwordx4 %2, %6, off sc0 sc1\n\t"
                "global_load_dwordx4 %3, %7, off sc0 sc1"
                : "=&v"(a0v), "=&v"(a1v), "=&v"(a2v), "=&v"(a3v)
                : "v"(p0), "v"(p1), "v"(p2), "v"(p3)
                : "memory");
            for (;;) {
                // issue set B (A still in flight)
                asm volatile(
                    "global_load_dwordx4 %0, %4, off sc0 sc1\n\t"
                    "global_load_dwordx4 %1, %5, off sc0 sc1\n\t"
                    "global_load_dwordx4 %2, %6, off sc0 sc1\n\t"
                    "global_load_dwordx4 %3, %7, off sc0 sc1"
                    : "=&v"(b0q), "=&v"(b1q), "=&v"(b2q), "=&v"(b3q)
                    : "v"(p0), "v"(p1), "v"(p2), "v"(p3)
                    : "memory");
                // wait for A (the 4 B loads remain outstanding); "+v" ties the check
                // AFTER the wait and keeps regs pinned while in flight
                asm volatile("s_waitcnt vmcnt(4)"
                    : "+v"(a0v), "+v"(a1v), "+v"(a2v), "+v"(a3v) :: "memory");
                unsigned bad = 0;
#pragma unroll
                for (int q = 0; q < 4; ++q)
                    bad |= (a0v[q] == SENT32) | (a1v[q] == SENT32)
                         | (a2v[q] == SENT32) | (a3v[q] == SENT32);
                if (!bad) {
                    asm volatile("s_waitcnt vmcnt(0)"
                        : "+v"(b0q), "+v"(b1q), "+v"(b2q), "+v"(b3q) :: "memory");
                    *(u32x4*)&hstage[(tid +   0) * 8] = a0v;
                    *(u32x4*)&hstage[(tid + 256) * 8] = a1v;
                    *(u32x4*)&hstage[(tid + 512) * 8] = a2v;
                    *(u32x4*)&hstage[(tid + 768) * 8] = a3v;
                    break;
                }
                // reissue set A (B still in flight)
                asm volatile(
                    "global_load_dwordx4 %0, %4, off sc0 sc1\n\t"
                    "global_load_dwordx4 %1, %5, off sc0 sc1\n\t"
                    "global_load_dwordx4 %2, %6, off sc0 sc1\n\t"
                    "global_load_dwordx4 %3, %7, off sc0 sc1"
                    : "=&v"(a0v), "=&v"(a1v), "=&v"(a2v), "=&v"(a3v)
                    : "v"(p0), "v"(p1), "v"(p2), "v"(p3)
                    : "memory");
                // wait for B (the 4 reissued A loads remain outstanding)
                asm volatile("s_waitcnt vmcnt(4)"
                    : "+v"(b0q), "+v"(b1q), "+v"(b2q), "+v"(b3q) :: "memory");
                bad = 0;
#pragma unroll
                for (int q = 0; q < 4; ++q)
                    bad |= (b0q[q] == SENT32) | (b1q[q] == SENT32)
                         | (b2q[q] == SENT32) | (b3q[q] == SENT32);
                if (!bad) {
                    asm volatile("s_waitcnt vmcnt(0)"
                        : "+v"(a0v), "+v"(a1v), "+v"(a2v), "+v"(a3v) :: "memory");
                    *(u32x4*)&hstage[(tid +   0) * 8] = b0q;
                    *(u32x4*)&hstage[(tid + 256) * 8] = b1q;
                    *(u32x4*)&hstage[(tid + 512) * 8] = b2q;
                    *(u32x4*)&hstage[(tid + 768) * 8] = b3q;
                    break;
                }
            }
        }
        __syncthreads();

        // ---- recurrent preactivation via MFMA (A fragments from LDS) ----
        f32x4 acc0 = {0.f, 0.f, 0.f, 0.f};
        f32x4 acc1 = {0.f, 0.f, 0.f, 0.f};
#pragma unroll
        for (int ks = 0; ks < 16; ++ks) {
            short8 a = *(const short8*)&hstage[ks * 512 + lane * 8];
            acc0 = __builtin_amdgcn_mfma_f32_16x16x32_bf16(a, bf[0][ks], acc0, 0, 0, 0);
            acc1 = __builtin_amdgcn_mfma_f32_16x16x32_bf16(a, bf[1][ks], acc1, 0, 0, 0);
        }

        // ---- scatter D to LDS: sg[gate][lk][b] ----
        {
            int r0 = (w * 2 + 0) * 16 + nl;
            int r1 = (w * 2 + 1) * 16 + nl;
            int g0r = r0 >> 5, lk0 = r0 & 31;
            int g1r = r1 >> 5, lk1 = r1 & 31;
#pragma unroll
            for (int reg = 0; reg < 4; ++reg) {
                int b = quad * 4 + reg;
                sg[g0r][lk0][b] = acc0[reg];
                sg[g1r][lk1][b] = acc1[reg];
            }
        }
        __syncthreads();

        // ---- epilogue: gates + state update, publish ASAP, then Hout ----
        int i0 = 0, i1 = 0;
        if (kok) {
#pragma unroll
            for (int p = 0; p < 2; ++p) {
                int b = p ? b1v : b0v;
                float si  = sg[0][lk][b] + h2f(gpraw[p][0]);
                float sf  = sg[1][lk][b] + h2f(gpraw[p][1]);
                float sgg = sg[2][lk][b] + h2f(gpraw[p][2]);
                float so  = sg[3][lk][b] + h2f(gpraw[p][3]);
                float ig = 1.f / (1.f + __expf(-si));
                float fg = 1.f / (1.f + __expf(-sf));
                float gg = tanhf(sgg);
                float og = 1.f / (1.f + __expf(-so));
                float c_new = fg * c_st[p] + ig * gg;
                float h_new = og * tanhf(c_new);
                float hn = m[p] ? h_new : h_st[p];
                float cn = m[p] ? c_new : c_st[p];
                h_st[p] = hn; c_st[p] = cn;
            }
            i0 = (int)(unsigned short)f2bf(h_st[0]);
            i1 = (int)(unsigned short)f2bf(h_st[1]);
        }

        // ---- publish h into buf[s+1] (ALL slots; 8B atomic stores; no barrier) ----
        {
            int a0 = __shfl_down(i0, 1), c0s = __shfl_down(i0, 2), d0 = __shfl_down(i0, 3);
            int a1 = __shfl_down(i1, 1), c1s = __shfl_down(i1, 2), d1 = __shfl_down(i1, 3);
            if ((lk & 3) == 0) {
                unsigned long long p0 = (unsigned long long)(unsigned)(i0 | (a0 << 16))
                                      | ((unsigned long long)(unsigned)(c0s | (d0 << 16)) << 32);
                unsigned long long p1 = (unsigned long long)(unsigned)(i1 | (a1 << 16))
                                      | ((unsigned long long)(unsigned)(c1s | (d1 << 16)) << 32);
                int idx0 = bsl * 512 + (b0v + 16 * (lk >> 3)) * 8 + (lk & 7);
                int idx1 = bsl * 512 + (b1v + 16 * (lk >> 3)) * 8 + (lk & 7);
                __hip_atomic_store((unsigned long long*)(bufw + idx0), p0,
                                   __ATOMIC_RELAXED, __HIP_MEMORY_SCOPE_AGENT);
                __hip_atomic_store((unsigned long long*)(bufw + idx1), p1,
                                   __ATOMIC_RELAXED, __HIP_MEMORY_SCOPE_AGENT);
            }
        }

        // ---- Hout (bf16, stride 1024): same bits as published; after publish ----
        if (kok) {
            Hout[((size_t)t * BB + b0v) * 1024 + dir * HD + k] =
                (unsigned short)(m[0] ? i0 : 0);
            Hout[((size_t)t * BB + b1v) * 1024 + dir * HD + k] =
                (unsigned short)(m[1] ? i1 : 0);
        }

        // ---- prefetch next step's G (raw) + mask: overlaps next poll-stage ----
        if (s + 1 < L) {
            int tn = dir ? (L - 2 - s) : (s + 1);
            if (kok) {
                const unsigned short* gr0 = Gd + ((size_t)tn * BB + b0v) * 2000 + k;
                const unsigned short* gr1 = Gd + ((size_t)tn * BB + b1v) * 2000 + k;
                gpraw[0][0] = gr0[0]; gpraw[0][1] = gr0[HD]; gpraw[0][2] = gr0[2 * HD]; gpraw[0][3] = gr0[3 * HD];
                gpraw[1][0] = gr1[0]; gpraw[1][1] = gr1[HD]; gpraw[1][2] = gr1[2 * HD]; gpraw[1][3] = gr1[3 * HD];
                m[0] = x[b0v * TT + tn] > 0;
                m[1] = x[b1v * TT + tn] > 0;
            }
        }
    }
}

// -------- output projection: Y (T,B,32) = bf16HS @ Wo^T + bo, masked ----------------
__global__ void outproj_kernel(const unsigned short* __restrict__ HS,
                               const float* __restrict__ Wo,
                               const float* __restrict__ bo, const int* __restrict__ x,
                               float* __restrict__ Y) {
    int idx = blockIdx.x * 256 + threadIdx.x;
    int r = idx >> 5;
    int n = idx & 31;
    int t = r >> 4;
    int b = r & 15;
    float out = 0.f;
    if (x[b * TT + t] > 0) {
        const unsigned short* h = HS + (size_t)r * 1024;
        const float* wrow = Wo + (size_t)n * 1000;
        float s = 0.f;
#pragma unroll 4
        for (int q = 0; q < 1000; q += 8) {
            short8 hv = *(const short8*)(h + q);
            float4 w0 = *(const float4*)(wrow + q);
            float4 w1 = *(const float4*)(wrow + q + 4);
            s += bf2f((unsigned short)hv[0]) * w0.x + bf2f((unsigned short)hv[1]) * w0.y
               + bf2f((unsigned short)hv[2]) * w0.z + bf2f((unsigned short)hv[3]) * w0.w
               + bf2f((unsigned short)hv[4]) * w1.x + bf2f((unsigned short)hv[5]) * w1.y
               + bf2f((unsigned short)hv[6]) * w1.z + bf2f((unsigned short)hv[7]) * w1.w;
        }
        out = s + bo[n];
    }
    Y[idx] = out;
}

// ---------------- CRF: gold score + forward scan ----------------
__global__ __launch_bounds__(1024) void crf_kernel(
    const float* __restrict__ Y, const int* __restrict__ x, const int* __restrict__ y0,
    const float* __restrict__ trans, float* __restrict__ out_pb) {
    int b = blockIdx.x;
    int tid = threadIdx.x;
    int i = tid >> 5;
    int j = tid & 31;
    float tr_ij = trans[i * 32 + j];

    __shared__ float sc[32];
    __shared__ float wred[16];
    __shared__ float goldS;

    float gp = 0.f;
    if (tid < TT) {
        int t = tid;
        int xm = x[b * TT + t];
        float mf = (xm > 0) ? 1.f : 0.f;
        int ynext = y0[b * TT + t];
        int yprev = (t == 0) ? 1 : y0[b * TT + t - 1];
        gp = Y[((size_t)t * BB + b) * 32 + ynext] + trans[ynext * 32 + yprev] * mf;
    }
#pragma unroll
    for (int d = 32; d >= 1; d >>= 1) gp += __shfl_down(gp, d);
    if ((tid & 63) == 0) wred[tid >> 6] = gp;
    __syncthreads();
    if (tid == 0) {
        float s = 0.f;
        for (int ww = 0; ww < 16; ++ww) s += wred[ww];
        goldS = s;
    }
    if (tid < 32) sc[tid] = (tid == 1) ? 0.f : NEG;
    __syncthreads();

    for (int t = 0; t < TT; ++t) {
        float sj = sc[j];
        float z = sj + tr_ij;
        float mx = z;
#pragma unroll
        for (int d = 16; d >= 1; d >>= 1) mx = fmaxf(mx, __shfl_xor(mx, d));
        float e = __expf(z - mx);
#pragma unroll
        for (int d = 16; d >= 1; d >>= 1) e += __shfl_xor(e, d);
        float cm = sj;
#pragma unroll
        for (int d = 16; d >= 1; d >>= 1) cm = fmaxf(cm, __shfl_xor(cm, d));
        float emit_i = Y[((size_t)t * BB + b) * 32 + i];
        float newv = emit_i + mx + __logf(e);
        int mm = x[b * TT + t] > 0;
        __syncthreads();
        if (j == 0) sc[i] = mm ? newv : cm;
        __syncthreads();
    }

    if (tid < 32) {
        float v = sc[tid];
        float mx = v;
#pragma unroll
        for (int d = 16; d >= 1; d >>= 1) mx = fmaxf(mx, __shfl_xor(mx, d));
        float e = __expf(v - mx);
#pragma unroll
        for (int d = 16; d >= 1; d >>= 1) e += __shfl_xor(e, d);
        if (tid == 0) out_pb[b] = (mx + __logf(e)) - goldS;
    }
}

__global__ void final_kernel(const float* __restrict__ out_pb, float* __restrict__ out) {
    if (threadIdx.x == 0 && blockIdx.x == 0) {
        float s = 0.f;
        for (int b = 0; b < BB; ++b) s += out_pb[b];
        out[0] = s / (float)BB;
    }
}

extern "C" void kernel_launch(void* const* d_in, const int* in_sizes, int n_in,
                              void* d_out, int out_size, void* d_ws, size_t ws_size,
                              hipStream_t stream) {
    const int*   x     = (const int*)d_in[0];
    const int*   y0    = (const int*)d_in[1];
    const float* EW    = (const float*)d_in[2];
    const float* Wih0  = (const float*)d_in[3];
    const float* Whh0  = (const float*)d_in[4];
    const float* bih0  = (const float*)d_in[5];
    const float* bhh0  = (const float*)d_in[6];
    const float* Wih1  = (const float*)d_in[7];
    const float* Whh1  = (const float*)d_in[8];
    const float* bih1  = (const float*)d_in[9];
    const float* bhh1  = (const float*)d_in[10];
    const float* Wo    = (const float*)d_in[11];
    const float* bo    = (const float*)d_in[12];
    const float* trans = (const float*)d_in[13];
    const float* h0    = (const float*)d_in[14];
    const float* c0    = (const float*)d_in[15];

    float* ws = (float*)d_ws;
    // Layout (float offsets), total 31,803,393 floats = 127.2 MB (< R3-proven 134 MB):
    //   [0, 524288)            XS bf16 (8192x128); Y fp32(262144)+crfbuf alias
    //   [524288, 16908288)     Gh: fp16 (2, 8192, 2000)
    //   [16908288, 21102592)   H0 bf16 (8192 x 1024)
    //   [21102592, 25296896)   HS bf16 (8192 x 1024)
    //   [25296896, 25552896)   Wb0 bf16 (2,2000,128)
    //   [25552896, 27600896)   Wb1 bf16 (2,2000,1024)
    //   [27600896, 31803392)   hseq: 2 dirs x 513 x 8192 bf16 (shared by both layers)
    //   [31803392]             mlen (1 int)
    unsigned short* XS = (unsigned short*)ws;
    float* Y      = ws;
    float* crfbuf = ws + 262144;
    unsigned short* Gh   = (unsigned short*)(ws + 524288);
    unsigned short* H0b  = (unsigned short*)(ws + 16908288);
    unsigned short* HSb  = (unsigned short*)(ws + 21102592);
    unsigned short* Wb0  = (unsigned short*)(ws + 25296896);
    unsigned short* Wb1  = (unsigned short*)(ws + 25552896);
    unsigned short* hseq = (unsigned short*)(ws + 27600896);
    int* mlen     = (int*)(ws + 31803392);
    const int nsent64 = 2 * (TT + 1) * 8192 / 4;   // 2,101,248 u64 words

    // Phase 0: maxlen + sentinel fill #1
    maxlen_kernel<<<1, 512, 0, stream>>>(x, mlen);
    sentfill_kernel<<<(nsent64 + 255) / 256, 256, 0, stream>>>((unsigned long long*)hseq, nsent64);

    // Phase 1: embedding -> bf16 XS (padded K=128); weight conversions
    embed_kernel<<<4096, 256, 0, stream>>>(x, EW, XS);
    wconv_kernel<<<(512000 + 255) / 256, 256, 0, stream>>>(Wih0, Wb0, 100, 128, 512000);
    wconv_kernel<<<(4096000 + 255) / 256, 256, 0, stream>>>(Wih1, Wb1, 1000, 1024, 4096000);

    // Phase 2: layer-0 input projections (MFMA, Kpad=128) -> fp16 Gh; zero H0 pads
    gemm_mfma<<<dim3(64, 32, 2), 256, 0, stream>>>(XS, Wb0, bih0, bhh0, Gh, 128);
    padzero_kernel<<<(98304 + 255) / 256, 256, 0, stream>>>((int*)H0b);

    // Phase 3: layer-0 recurrence -> bf16 H0 (32 blocks spread; staggered polling)
    rec10_kernel<<<32, 256, 0, stream>>>(Gh, Whh0, x, h0, c0, 0, H0b, hseq, mlen);

    // Phase 4: layer-1 input projections (MFMA, Kpad=1024) -> fp16 Gh; refill hseq
    gemm_mfma<<<dim3(64, 32, 2), 256, 0, stream>>>(H0b, Wb1, bih1, bhh1, Gh, 1024);
    sentfill_kernel<<<(nsent64 + 255) / 256, 256, 0, stream>>>((unsigned long long*)hseq, nsent64);

    // Phase 5: layer-1 recurrence -> bf16 HS
    rec10_kernel<<<32, 256, 0, stream>>>(Gh, Whh1, x, h0, c0, 2, HSb, hseq, mlen);

    // Phase 6: output projection (masked; bf16 HS, stride 1024)
    outproj_kernel<<<1024, 256, 0, stream>>>(HSb, Wo, bo, x, Y);

    // Phase 7: CRF gold + forward scan
    crf_kernel<<<BB, 1024, 0, stream>>>(Y, x, y0, trans, crfbuf);

    // Phase 8: mean
    final_kernel<<<1, 64, 0, stream>>>(crfbuf, (float*)d_out);
}

// Round 4
// 3060.192 us; speedup vs baseline: 1.1633x; 1.0851x over previous
//
#include <hip/hip_runtime.h>
#include <hip/hip_fp16.h>
#include <math.h>

#define TT 512
#define BB 16
#define EE 100
#define HD 500
#define NEG (-10000.0f)
#define SENT64 0xFFFFFFFFFFFFFFFFull
#define SENT32 0xFFFFFFFFu

typedef __attribute__((ext_vector_type(8))) short short8;
typedef __attribute__((ext_vector_type(4))) float f32x4;
typedef __attribute__((ext_vector_type(4))) unsigned int u32x4;

__device__ inline short f2bf(float f) {
    unsigned u = __builtin_bit_cast(unsigned, f);
    unsigned r = (u + 0x7fffu + ((u >> 16) & 1u)) >> 16;
    return (short)r;
}
__device__ inline unsigned short f2h(float f) {
    __half h = __float2half(f);
    return __builtin_bit_cast(unsigned short, h);
}
__device__ inline float h2f(unsigned short u) {
    __half h = __builtin_bit_cast(__half, u);
    return __half2float(h);
}
__device__ inline float bf2f(unsigned short u) {
    return __builtin_bit_cast(float, ((unsigned)u) << 16);
}

// ---------------- maxlen: 1 + max t with any x[b,t] > 0 ----------------
__global__ void maxlen_kernel(const int* __restrict__ x, int* __restrict__ out) {
    __shared__ int mx;
    int t = threadIdx.x;          // 512 threads
    if (t == 0) mx = 1;
    __syncthreads();
    int any = 0;
    for (int b = 0; b < BB; ++b) any |= (x[b * TT + t] > 0);
    if (any) atomicMax(&mx, t + 1);
    __syncthreads();
    if (t == 0) out[0] = mx;
}

// ---------------- sentinel fill via agent-scope atomic stores (MALL-visible) -------
__global__ void sentfill_kernel(unsigned long long* __restrict__ p, int n) {
    int i = blockIdx.x * 256 + threadIdx.x;
    if (i < n)
        __hip_atomic_store(p + i, SENT64, __ATOMIC_RELAXED, __HIP_MEMORY_SCOPE_AGENT);
}

// ---------------- embedding gather -> bf16 XS (T*B, 128) zero-padded ----------------
__global__ void embed_kernel(const int* __restrict__ x, const float* __restrict__ EW,
                             unsigned short* __restrict__ XS) {
    int idx = blockIdx.x * 256 + threadIdx.x;    // < 8192*128
    int e = idx & 127;
    int r = idx >> 7;          // r = t*16 + b
    int t = r >> 4;
    int b = r & 15;
    unsigned short v = 0;
    if (e < EE) {
        int tok = x[b * TT + t];
        v = (unsigned short)f2bf(EW[(size_t)tok * EE + e]);
    }
    XS[idx] = v;
}

// ---------------- fp32 -> bf16 weight conversion with K padding ----------------
__global__ void wconv_kernel(const float* __restrict__ src, unsigned short* __restrict__ dst,
                             int Ksrc, int Kpad, int total) {
    int i = blockIdx.x * 256 + threadIdx.x;
    if (i >= total) return;
    int r = i / Kpad;
    int k = i - r * Kpad;
    dst[i] = (k < Ksrc) ? (unsigned short)f2bf(src[(size_t)r * Ksrc + k]) : 0;
}

// ---------------- zero the pad columns (1000..1023) of bf16 H0 ----------------
__global__ void padzero_kernel(int* __restrict__ p) {
    int i = blockIdx.x * 256 + threadIdx.x;      // < 8192*12
    if (i >= 8192 * 12) return;
    int r = i / 12, c = i - r * 12;
    p[r * 512 + 500 + c] = 0;                    // shorts 1000..1023 = ints 500..511
}

// ------------- bf16 MFMA GEMM: C[z] = f16(A @ W[z]^T + b1[z] + b2[z]) --------------
// A: (8192, Kpad) bf16. W: (2, 2000, Kpad) bf16. C: (2, 8192, 2000) fp16.
// Round-4: software-pipelined global loads (issue tile k+1 right after the second
// barrier, before fragment reads + MFMA of tile k) -> load RTT overlaps compute.
// Same LDS layout, same MFMA order -> bit-identical output.
__global__ __launch_bounds__(256) void gemm_mfma(
    const unsigned short* __restrict__ A, const unsigned short* __restrict__ W,
    const float* __restrict__ b1, const float* __restrict__ b2,
    unsigned short* __restrict__ C, int Kpad) {
    __shared__ __align__(16) unsigned short AsS[128 * 40];
    __shared__ __align__(16) unsigned short WsS[64 * 40];
    const int tid = threadIdx.x;
    const int lane = tid & 63;
    const int w = tid >> 6;
    const int quad = lane >> 4;
    const int nl = lane & 15;
    const int bm0 = blockIdx.x * 128;
    const int n0 = blockIdx.y * 64;
    const int z = blockIdx.z;

    const unsigned short* Wz = W + (size_t)z * 2000 * Kpad;
    unsigned short* Cz = C + (size_t)z * 8192 * 2000;
    const float* b1z = b1 + (size_t)z * 2000;
    const float* b2z = b2 + (size_t)z * 2000;

    f32x4 acc[2][4];
#pragma unroll
    for (int mt = 0; mt < 2; ++mt)
#pragma unroll
        for (int nt = 0; nt < 4; ++nt) acc[mt][nt] = (f32x4){0.f, 0.f, 0.f, 0.f};

    const int arow = tid >> 2;
    const int kc = tid & 3;
    const int wn = n0 + arow;
    const bool wok = (wn < 2000);

    const unsigned short* Ap0 = A + (size_t)(bm0 + arow) * Kpad + kc * 8;
    const unsigned short* Ap1 = A + (size_t)(bm0 + 64 + arow) * Kpad + kc * 8;
    const unsigned short* Wp  = Wz + (size_t)(wok ? wn : 0) * Kpad + kc * 8;

    // preload tile 0
    short8 av0 = *(const short8*)(Ap0);
    short8 av1 = *(const short8*)(Ap1);
    short8 wv = {0, 0, 0, 0, 0, 0, 0, 0};
    if (wok) wv = *(const short8*)(Wp);

    for (int k0 = 0; k0 < Kpad; k0 += 32) {
        __syncthreads();           // prior iteration's fragment reads done (WAR)
        *(short8*)&AsS[arow * 40 + kc * 8] = av0;
        *(short8*)&AsS[(64 + arow) * 40 + kc * 8] = av1;
        *(short8*)&WsS[arow * 40 + kc * 8] = wv;
        __syncthreads();

        // issue next tile's loads now; latency hides under LDS reads + MFMA
        if (k0 + 32 < Kpad) {
            av0 = *(const short8*)(Ap0 + k0 + 32);
            av1 = *(const short8*)(Ap1 + k0 + 32);
            if (wok) wv = *(const short8*)(Wp + k0 + 32);
        }

        short8 af[2], bfr[4];
#pragma unroll
        for (int mt = 0; mt < 2; ++mt)
            af[mt] = *(const short8*)&AsS[(w * 32 + mt * 16 + nl) * 40 + quad * 8];
#pragma unroll
        for (int nt = 0; nt < 4; ++nt)
            bfr[nt] = *(const short8*)&WsS[(nt * 16 + nl) * 40 + quad * 8];
#pragma unroll
        for (int mt = 0; mt < 2; ++mt)
#pragma unroll
            for (int nt = 0; nt < 4; ++nt)
                acc[mt][nt] = __builtin_amdgcn_mfma_f32_16x16x32_bf16(
                    af[mt], bfr[nt], acc[mt][nt], 0, 0, 0);
    }

#pragma unroll
    for (int nt = 0; nt < 4; ++nt) {
        int n = n0 + nt * 16 + nl;
        if (n < 2000) {
            float bb = b1z[n] + b2z[n];
#pragma unroll
            for (int mt = 0; mt < 2; ++mt) {
                int mbase = bm0 + w * 32 + mt * 16 + quad * 4;
#pragma unroll
                for (int reg = 0; reg < 4; ++reg)
                    Cz[(size_t)(mbase + reg) * 2000 + n] = f2h(acc[mt][nt][reg] + bb);
            }
        }
    }
}

// ---------------- persistent-weight recurrence, bf16 MFMA, DATA-IS-FLAG sync -------
// VERBATIM the proven 3127-us baseline (round-0 input). hseq: per dir, (TT+1)
// write-once buffers of 8192 bf16 in MFMA-A layout, pre-filled with 0xFFFF sentinels
// via agent-scope atomic stores. Producer at step s publishes buf[s+1] with 8B
// agent-scope atomic stores (ALL slots, zeros for k>=HD). Consumer stages buf[s] into
// LDS with sc0/sc1 dwordx4 loads, retrying any 4B word that still reads 0xFFFFFFFF
// (two bf16 NaNs -- unreachable from f2bf of finite h). Stale reads can only return
// SENT (write-once buffers) -> retry, never wrong data. No fences, no barriers.
__global__ __launch_bounds__(256, 1) void rec10_kernel(
    const unsigned short* __restrict__ G, const float* __restrict__ Whh,
    const int* __restrict__ x, const float* __restrict__ h0,
    const float* __restrict__ c0, int layerbase,
    unsigned short* __restrict__ Hout, unsigned short* __restrict__ hseq,
    const int* __restrict__ mlen)
{
    const int blk = blockIdx.x;
    const int dir = blk >> 4;
    const int bsl = blk & 15;
    const int k0 = bsl * 32;
    const int tid = threadIdx.x;
    const int lane = tid & 63;
    const int w = tid >> 6;          // wave 0..3
    const int quad = lane >> 4;      // 0..3
    const int nl = lane & 15;
    const int L = mlen[0];           // 1..512

    const float* Wd = Whh + (size_t)dir * 2000 * HD;
    const unsigned short* Gd = G + (size_t)dir * TT * BB * 2000;
    unsigned short* hdir = hseq + (size_t)dir * (TT + 1) * 8192;

    __shared__ __align__(16) unsigned short hstage[8192];
    __shared__ float sg[4][32][17];

    // ---- load weights into registers as B fragments (bf16) ----
    short8 bf[2][16];
#pragma unroll
    for (int tl = 0; tl < 2; ++tl) {
        int tt = w * 2 + tl;
        int r = tt * 16 + nl;          // 0..127 local gate row
        int g = r >> 5;                // gate 0..3
        int lkr = r & 31;
        int kk = k0 + lkr;             // output h index
        const float* wrow = (kk < HD) ? (Wd + (size_t)(g * HD + kk) * HD) : (const float*)0;
#pragma unroll
        for (int ks = 0; ks < 16; ++ks) {
            int kg0 = ks * 32 + quad * 8;
            short8 v;
            if (wrow && kg0 + 8 <= HD) {
                float4 f0 = *(const float4*)(wrow + kg0);
                float4 f1 = *(const float4*)(wrow + kg0 + 4);
                v[0] = f2bf(f0.x); v[1] = f2bf(f0.y); v[2] = f2bf(f0.z); v[3] = f2bf(f0.w);
                v[4] = f2bf(f1.x); v[5] = f2bf(f1.y); v[6] = f2bf(f1.z); v[7] = f2bf(f1.w);
            } else {
#pragma unroll
                for (int j = 0; j < 8; ++j) {
                    int kg = kg0 + j;
                    float f = (wrow && kg < HD) ? wrow[kg] : 0.f;
                    v[j] = f2bf(f);
                }
            }
            bf[tl][ks] = v;
        }
    }

    // ---- per-thread persistent state: 2 (b,k) pairs, same k different b ----
    const int lk = tid & 31;
    const int k  = k0 + lk;
    const bool kok = (k < HD);
    const int b0v = tid >> 5;          // 0..7
    const int b1v = 8 + (tid >> 5);    // 8..15
    float h_st[2] = {0.f, 0.f}, c_st[2] = {0.f, 0.f};
    if (kok) {
        size_t base0 = (size_t)(layerbase + dir) * BB * HD + (size_t)b0v * HD + k;
        size_t base1 = (size_t)(layerbase + dir) * BB * HD + (size_t)b1v * HD + k;
        h_st[0] = h0[base0]; c_st[0] = c0[base0];
        h_st[1] = h0[base1]; c_st[1] = c0[base1];
    }

    // ---- publish h0 into buf[0] (ALL slots: zeros for k>=HD; 8B atomic stores) ----
    {
        int i0 = (int)(unsigned short)f2bf(kok ? h_st[0] : 0.f);
        int i1 = (int)(unsigned short)f2bf(kok ? h_st[1] : 0.f);
        int a0 = __shfl_down(i0, 1), c0s = __shfl_down(i0, 2), d0 = __shfl_down(i0, 3);
        int a1 = __shfl_down(i1, 1), c1s = __shfl_down(i1, 2), d1 = __shfl_down(i1, 3);
        if ((lk & 3) == 0) {
            unsigned long long p0 = (unsigned long long)(unsigned)(i0 | (a0 << 16))
                                  | ((unsigned long long)(unsigned)(c0s | (d0 << 16)) << 32);
            unsigned long long p1 = (unsigned long long)(unsigned)(i1 | (a1 << 16))
                                  | ((unsigned long long)(unsigned)(c1s | (d1 << 16)) << 32);
            int idx0 = bsl * 512 + (b0v + 16 * (lk >> 3)) * 8 + (lk & 7);
            int idx1 = bsl * 512 + (b1v + 16 * (lk >> 3)) * 8 + (lk & 7);
            __hip_atomic_store((unsigned long long*)(hdir + idx0), p0,
                               __ATOMIC_RELAXED, __HIP_MEMORY_SCOPE_AGENT);
            __hip_atomic_store((unsigned long long*)(hdir + idx1), p1,
                               __ATOMIC_RELAXED, __HIP_MEMORY_SCOPE_AGENT);
        }
    }

    // ---- prefetch step-0 G (raw) + mask ----
    unsigned short gpraw[2][4]; int m[2];
    m[0] = m[1] = 0;
    gpraw[0][0]=gpraw[0][1]=gpraw[0][2]=gpraw[0][3]=0;
    gpraw[1][0]=gpraw[1][1]=gpraw[1][2]=gpraw[1][3]=0;
    {
        int t = dir ? (L - 1) : 0;
        if (kok) {
            const unsigned short* gr0 = Gd + ((size_t)t * BB + b0v) * 2000 + k;
            const unsigned short* gr1 = Gd + ((size_t)t * BB + b1v) * 2000 + k;
            gpraw[0][0] = gr0[0]; gpraw[0][1] = gr0[HD]; gpraw[0][2] = gr0[2 * HD]; gpraw[0][3] = gr0[3 * HD];
            gpraw[1][0] = gr1[0]; gpraw[1][1] = gr1[HD]; gpraw[1][2] = gr1[2 * HD]; gpraw[1][3] = gr1[3 * HD];
            m[0] = x[b0v * TT + t] > 0;
            m[1] = x[b1v * TT + t] > 0;
        }
    }

    for (int s = 0; s < L; ++s) {
        const int t = dir ? (L - 1 - s) : s;
        const unsigned short* bufr = hdir + (size_t)s * 8192;
        unsigned short* bufw = hdir + (size_t)(s + 1) * 8192;

        // ---- poll-stage buf[s] into LDS: per-thread 4x16B sc0/sc1 loads, retry
        //      until no 4B word is the sentinel (data-is-flag) ----
        {
            const unsigned short* p0 = bufr + (tid +   0) * 8;
            const unsigned short* p1 = bufr + (tid + 256) * 8;
            const unsigned short* p2 = bufr + (tid + 512) * 8;
            const unsigned short* p3 = bufr + (tid + 768) * 8;
            u32x4 c0v, c1v, c2v, c3v;
            for (;;) {
                asm volatile(
                    "global_load_dwordx4 %0, %4, off sc0 sc1\n\t"
                    "global_load_dwordx4 %1, %5, off sc0 sc1\n\t"
                    "global_load_dwordx4 %2, %6, off sc0 sc1\n\t"
                    "global_load_dwordx4 %3, %7, off sc0 sc1\n\t"
                    "s_waitcnt vmcnt(0)"
                    : "=&v"(c0v), "=&v"(c1v), "=&v"(c2v), "=&v"(c3v)
                    : "v"(p0), "v"(p1), "v"(p2), "v"(p3)
                    : "memory");
                unsigned bad = 0;
#pragma unroll
                for (int q = 0; q < 4; ++q)
                    bad |= (c0v[q] == SENT32) | (c1v[q] == SENT32)
                         | (c2v[q] == SENT32) | (c3v[q] == SENT32);
                if (!bad) break;
            }
            *(u32x4*)&hstage[(tid +   0) * 8] = c0v;
            *(u32x4*)&hstage[(tid + 256) * 8] = c1v;
            *(u32x4*)&hstage[(tid + 512) * 8] = c2v;
            *(u32x4*)&hstage[(tid + 768) * 8] = c3v;
        }
        __syncthreads();

        // ---- recurrent preactivation via MFMA (A fragments from LDS) ----
        f32x4 acc0 = {0.f, 0.f, 0.f, 0.f};
        f32x4 acc1 = {0.f, 0.f, 0.f, 0.f};
#pragma unroll
        for (int ks = 0; ks < 16; ++ks) {
            short8 a = *(const short8*)&hstage[ks * 512 + lane * 8];
            acc0 = __builtin_amdgcn_mfma_f32_16x16x32_bf16(a, bf[0][ks], acc0, 0, 0, 0);
            acc1 = __builtin_amdgcn_mfma_f32_16x16x32_bf16(a, bf[1][ks], acc1, 0, 0, 0);
        }

        // ---- scatter D to LDS: sg[gate][lk][b] ----
        {
            int r0 = (w * 2 + 0) * 16 + nl;
            int r1 = (w * 2 + 1) * 16 + nl;
            int g0r = r0 >> 5, lk0 = r0 & 31;
            int g1r = r1 >> 5, lk1 = r1 & 31;
#pragma unroll
            for (int reg = 0; reg < 4; ++reg) {
                int b = quad * 4 + reg;
                sg[g0r][lk0][b] = acc0[reg];
                sg[g1r][lk1][b] = acc1[reg];
            }
        }
        __syncthreads();

        // ---- epilogue: gates, state update, Hout (bf16, stride 1024) ----
        if (kok) {
#pragma unroll
            for (int p = 0; p < 2; ++p) {
                int b = p ? b1v : b0v;
                float si  = sg[0][lk][b] + h2f(gpraw[p][0]);
                float sf  = sg[1][lk][b] + h2f(gpraw[p][1]);
                float sgg = sg[2][lk][b] + h2f(gpraw[p][2]);
                float so  = sg[3][lk][b] + h2f(gpraw[p][3]);
                float ig = 1.f / (1.f + __expf(-si));
                float fg = 1.f / (1.f + __expf(-sf));
                float gg = tanhf(sgg);
                float og = 1.f / (1.f + __expf(-so));
                float c_new = fg * c_st[p] + ig * gg;
                float h_new = og * tanhf(c_new);
                float hn = m[p] ? h_new : h_st[p];
                float cn = m[p] ? c_new : c_st[p];
                h_st[p] = hn; c_st[p] = cn;
                Hout[((size_t)t * BB + b) * 1024 + dir * HD + k] =
                    (unsigned short)f2bf(m[p] ? h_new : 0.f);
            }
        }

        // ---- publish h into buf[s+1] (ALL slots; 8B atomic stores; no barrier) ----
        {
            int i0 = (int)(unsigned short)f2bf(kok ? h_st[0] : 0.f);
            int i1 = (int)(unsigned short)f2bf(kok ? h_st[1] : 0.f);
            int a0 = __shfl_down(i0, 1), c0s = __shfl_down(i0, 2), d0 = __shfl_down(i0, 3);
            int a1 = __shfl_down(i1, 1), c1s = __shfl_down(i1, 2), d1 = __shfl_down(i1, 3);
            if ((lk & 3) == 0) {
                unsigned long long p0 = (unsigned long long)(unsigned)(i0 | (a0 << 16))
                                      | ((unsigned long long)(unsigned)(c0s | (d0 << 16)) << 32);
                unsigned long long p1 = (unsigned long long)(unsigned)(i1 | (a1 << 16))
                                      | ((unsigned long long)(unsigned)(c1s | (d1 << 16)) << 32);
                int idx0 = bsl * 512 + (b0v + 16 * (lk >> 3)) * 8 + (lk & 7);
                int idx1 = bsl * 512 + (b1v + 16 * (lk >> 3)) * 8 + (lk & 7);
                __hip_atomic_store((unsigned long long*)(bufw + idx0), p0,
                                   __ATOMIC_RELAXED, __HIP_MEMORY_SCOPE_AGENT);
                __hip_atomic_store((unsigned long long*)(bufw + idx1), p1,
                                   __ATOMIC_RELAXED, __HIP_MEMORY_SCOPE_AGENT);
            }
        }

        // ---- prefetch next step's G (raw) + mask: overlaps next poll-stage ----
        if (s + 1 < L) {
            int tn = dir ? (L - 2 - s) : (s + 1);
            if (kok) {
                const unsigned short* gr0 = Gd + ((size_t)tn * BB + b0v) * 2000 + k;
                const unsigned short* gr1 = Gd + ((size_t)tn * BB + b1v) * 2000 + k;
                gpraw[0][0] = gr0[0]; gpraw[0][1] = gr0[HD]; gpraw[0][2] = gr0[2 * HD]; gpraw[0][3] = gr0[3 * HD];
                gpraw[1][0] = gr1[0]; gpraw[1][1] = gr1[HD]; gpraw[1][2] = gr1[2 * HD]; gpraw[1][3] = gr1[3 * HD];
                m[0] = x[b0v * TT + tn] > 0;
                m[1] = x[b1v * TT + tn] > 0;
            }
        }
    }
}

// -------- output projection: Y (T,B,32) = bf16HS @ Wo^T + bo, masked ----------------
// Round-4: block retiled to 32 r x 8 n; the block's 8 Wo rows staged in LDS (32 KB
// f32) once -> per-thread Wo reads come from LDS broadcast instead of ~1 GB of L2
// traffic. Same f32 values, same accumulation order -> bit-identical Y.
__global__ __launch_bounds__(256) void outproj_kernel(
    const unsigned short* __restrict__ HS, const float* __restrict__ Wo,
    const float* __restrict__ bo, const int* __restrict__ x,
    float* __restrict__ Y) {
    __shared__ float wlds[8 * 1000];
    const int bid = blockIdx.x;          // 1024 blocks
    const int tid = threadIdx.x;         // 256
    const int rblk = bid >> 2;           // 0..255
    const int n0 = (bid & 3) * 8;        // 0,8,16,24
    for (int i = tid; i < 8000; i += 256) {
        int nn = i / 1000;
        int q = i - nn * 1000;
        wlds[i] = Wo[(size_t)(n0 + nn) * 1000 + q];
    }
    __syncthreads();
    const int r = rblk * 32 + (tid >> 3);
    const int n = n0 + (tid & 7);
    const int t = r >> 4;
    const int b = r & 15;
    float out = 0.f;
    if (x[b * TT + t] > 0) {
        const unsigned short* h = HS + (size_t)r * 1024;
        const float* wrow = &wlds[(tid & 7) * 1000];
        float s = 0.f;
#pragma unroll 4
        for (int q = 0; q < 1000; q += 8) {
            short8 hv = *(const short8*)(h + q);
            float4 w0 = *(const float4*)(wrow + q);
            float4 w1 = *(const float4*)(wrow + q + 4);
            s += bf2f((unsigned short)hv[0]) * w0.x + bf2f((unsigned short)hv[1]) * w0.y
               + bf2f((unsigned short)hv[2]) * w0.z + bf2f((unsigned short)hv[3]) * w0.w
               + bf2f((unsigned short)hv[4]) * w1.x + bf2f((unsigned short)hv[5]) * w1.y
               + bf2f((unsigned short)hv[6]) * w1.z + bf2f((unsigned short)hv[7]) * w1.w;
        }
        out = s + bo[n];
    }
    Y[(size_t)r * 32 + n] = out;
}

// ---------------- CRF: gold score + forward scan ----------------
// Round-4: double-buffered score vector (ONE barrier per timestep instead of two) +
// emit/mask prefetch for t+1 issued before t's reductions (hides the serial L2 load).
// Same math, same order -> bit-identical.
__global__ __launch_bounds__(1024) void crf_kernel(
    const float* __restrict__ Y, const int* __restrict__ x, const int* __restrict__ y0,
    const float* __restrict__ trans, float* __restrict__ out_pb) {
    int b = blockIdx.x;
    int tid = threadIdx.x;
    int i = tid >> 5;
    int j = tid & 31;
    float tr_ij = trans[i * 32 + j];

    __shared__ float scb[2][32];
    __shared__ float wred[16];
    __shared__ float goldS;

    float gp = 0.f;
    if (tid < TT) {
        int t = tid;
        int xm = x[b * TT + t];
        float mf = (xm > 0) ? 1.f : 0.f;
        int ynext = y0[b * TT + t];
        int yprev = (t == 0) ? 1 : y0[b * TT + t - 1];
        gp = Y[((size_t)t * BB + b) * 32 + ynext] + trans[ynext * 32 + yprev] * mf;
    }
#pragma unroll
    for (int d = 32; d >= 1; d >>= 1) gp += __shfl_down(gp, d);
    if ((tid & 63) == 0) wred[tid >> 6] = gp;
    __syncthreads();
    if (tid == 0) {
        float s = 0.f;
        for (int ww = 0; ww < 16; ++ww) s += wred[ww];
        goldS = s;
    }
    if (tid < 32) scb[0][tid] = (tid == 1) ? 0.f : NEG;
    __syncthreads();

    int cur = 0;
    float emit_c = Y[((size_t)0 * BB + b) * 32 + i];
    int mm_c = x[b * TT + 0] > 0;
    for (int t = 0; t < TT; ++t) {
        float emit_n = 0.f;
        int mm_n = 0;
        if (t + 1 < TT) {
            emit_n = Y[((size_t)(t + 1) * BB + b) * 32 + i];
            mm_n = x[b * TT + t + 1] > 0;
        }
        float sj = scb[cur][j];
        float z = sj + tr_ij;
        float mx = z;
#pragma unroll
        for (int d = 16; d >= 1; d >>= 1) mx = fmaxf(mx, __shfl_xor(mx, d));
        float e = __expf(z - mx);
#pragma unroll
        for (int d = 16; d >= 1; d >>= 1) e += __shfl_xor(e, d);
        float cm = sj;
#pragma unroll
        for (int d = 16; d >= 1; d >>= 1) cm = fmaxf(cm, __shfl_xor(cm, d));
        float newv = emit_c + mx + __logf(e);
        if (j == 0) scb[cur ^ 1][i] = mm_c ? newv : cm;
        __syncthreads();
        cur ^= 1;
        emit_c = emit_n;
        mm_c = mm_n;
    }

    if (tid < 32) {
        float v = scb[cur][tid];
        float mx = v;
#pragma unroll
        for (int d = 16; d >= 1; d >>= 1) mx = fmaxf(mx, __shfl_xor(mx, d));
        float e = __expf(v - mx);
#pragma unroll
        for (int d = 16; d >= 1; d >>= 1) e += __shfl_xor(e, d);
        if (tid == 0) out_pb[b] = (mx + __logf(e)) - goldS;
    }
}

__global__ void final_kernel(const float* __restrict__ out_pb, float* __restrict__ out) {
    if (threadIdx.x == 0 && blockIdx.x == 0) {
        float s = 0.f;
        for (int b = 0; b < BB; ++b) s += out_pb[b];
        out[0] = s / (float)BB;
    }
}

extern "C" void kernel_launch(void* const* d_in, const int* in_sizes, int n_in,
                              void* d_out, int out_size, void* d_ws, size_t ws_size,
                              hipStream_t stream) {
    const int*   x     = (const int*)d_in[0];
    const int*   y0    = (const int*)d_in[1];
    const float* EW    = (const float*)d_in[2];
    const float* Wih0  = (const float*)d_in[3];
    const float* Whh0  = (const float*)d_in[4];
    const float* bih0  = (const float*)d_in[5];
    const float* bhh0  = (const float*)d_in[6];
    const float* Wih1  = (const float*)d_in[7];
    const float* Whh1  = (const float*)d_in[8];
    const float* bih1  = (const float*)d_in[9];
    const float* bhh1  = (const float*)d_in[10];
    const float* Wo    = (const float*)d_in[11];
    const float* bo    = (const float*)d_in[12];
    const float* trans = (const float*)d_in[13];
    const float* h0    = (const float*)d_in[14];
    const float* c0    = (const float*)d_in[15];

    float* ws = (float*)d_ws;
    // Layout (float offsets), total 31,803,393 floats = 127.2 MB (< R3-proven 134 MB):
    //   [0, 524288)            XS bf16 (8192x128); Y fp32(262144)+crfbuf alias
    //   [524288, 16908288)     Gh: fp16 (2, 8192, 2000)
    //   [16908288, 21102592)   H0 bf16 (8192 x 1024)
    //   [21102592, 25296896)   HS bf16 (8192 x 1024)
    //   [25296896, 25552896)   Wb0 bf16 (2,2000,128)
    //   [25552896, 27600896)   Wb1 bf16 (2,2000,1024)
    //   [27600896, 31803392)   hseq: 2 dirs x 513 x 8192 bf16 (shared by both layers)
    //   [31803392]             mlen (1 int)
    unsigned short* XS = (unsigned short*)ws;
    float* Y      = ws;
    float* crfbuf = ws + 262144;
    unsigned short* Gh   = (unsigned short*)(ws + 524288);
    unsigned short* H0b  = (unsigned short*)(ws + 16908288);
    unsigned short* HSb  = (unsigned short*)(ws + 21102592);
    unsigned short* Wb0  = (unsigned short*)(ws + 25296896);
    unsigned short* Wb1  = (unsigned short*)(ws + 25552896);
    unsigned short* hseq = (unsigned short*)(ws + 27600896);
    int* mlen     = (int*)(ws + 31803392);
    const int nsent64 = 2 * (TT + 1) * 8192 / 4;   // 2,101,248 u64 words

    // Phase 0: maxlen + sentinel fill #1
    maxlen_kernel<<<1, 512, 0, stream>>>(x, mlen);
    sentfill_kernel<<<(nsent64 + 255) / 256, 256, 0, stream>>>((unsigned long long*)hseq, nsent64);

    // Phase 1: embedding -> bf16 XS (padded K=128); weight conversions
    embed_kernel<<<4096, 256, 0, stream>>>(x, EW, XS);
    wconv_kernel<<<(512000 + 255) / 256, 256, 0, stream>>>(Wih0, Wb0, 100, 128, 512000);
    wconv_kernel<<<(4096000 + 255) / 256, 256, 0, stream>>>(Wih1, Wb1, 1000, 1024, 4096000);

    // Phase 2: layer-0 input projections (MFMA, Kpad=128) -> fp16 Gh; zero H0 pads
    gemm_mfma<<<dim3(64, 32, 2), 256, 0, stream>>>(XS, Wb0, bih0, bhh0, Gh, 128);
    padzero_kernel<<<(98304 + 255) / 256, 256, 0, stream>>>((int*)H0b);

    // Phase 3: layer-0 recurrence -> bf16 H0 (data-is-flag, plain launch)
    rec10_kernel<<<32, 256, 0, stream>>>(Gh, Whh0, x, h0, c0, 0, H0b, hseq, mlen);

    // Phase 4: layer-1 input projections (MFMA, Kpad=1024) -> fp16 Gh; refill hseq
    gemm_mfma<<<dim3(64, 32, 2), 256, 0, stream>>>(H0b, Wb1, bih1, bhh1, Gh, 1024);
    sentfill_kernel<<<(nsent64 + 255) / 256, 256, 0, stream>>>((unsigned long long*)hseq, nsent64);

    // Phase 5: layer-1 recurrence -> bf16 HS
    rec10_kernel<<<32, 256, 0, stream>>>(Gh, Whh1, x, h0, c0, 2, HSb, hseq, mlen);

    // Phase 6: output projection (masked; bf16 HS, stride 1024; Wo staged in LDS)
    outproj_kernel<<<1024, 256, 0, stream>>>(HSb, Wo, bo, x, Y);

    // Phase 7: CRF gold + forward scan (single-barrier, prefetched)
    crf_kernel<<<BB, 1024, 0, stream>>>(Y, x, y0, trans, crfbuf);

    // Phase 8: mean
    final_kernel<<<1, 64, 0, stream>>>(crfbuf, (float*)d_out);
}

// Round 5
// 2616.183 us; speedup vs baseline: 1.3607x; 1.1697x over previous
//
#include <hip/hip_runtime.h>
#include <hip/hip_fp16.h>
#include <math.h>

#define TT 512
#define BB 16
#define EE 100
#define HD 500
#define NEG (-10000.0f)
#define SENT64 0xFFFFFFFFFFFFFFFFull
#define SENT32 0xFFFFFFFFu

typedef __attribute__((ext_vector_type(8))) short short8;
typedef __attribute__((ext_vector_type(4))) float f32x4;
typedef __attribute__((ext_vector_type(4))) unsigned int u32x4;

__device__ inline short f2bf(float f) {
    unsigned u = __builtin_bit_cast(unsigned, f);
    unsigned r = (u + 0x7fffu + ((u >> 16) & 1u)) >> 16;
    return (short)r;
}
__device__ inline unsigned short f2h(float f) {
    __half h = __float2half(f);
    return __builtin_bit_cast(unsigned short, h);
}
__device__ inline float h2f(unsigned short u) {
    __half h = __builtin_bit_cast(__half, u);
    return __half2float(h);
}
__device__ inline float bf2f(unsigned short u) {
    return __builtin_bit_cast(float, ((unsigned)u) << 16);
}
// fast sigmoid/tanh via v_exp+v_rcp (r2-verified: absmax 0.0). Correct saturation:
// exp overflow -> inf -> rcp -> 0 -> +/-1.
__device__ inline float sigm_fast(float x) {
    return __builtin_amdgcn_rcpf(1.f + __expf(-x));
}
__device__ inline float tanh_fast(float x) {
    return 1.f - 2.f * __builtin_amdgcn_rcpf(__expf(2.f * x) + 1.f);
}
// MALL write-through 2B store (same visibility mechanics as the h-publish stores)
__device__ inline void store_u16_wt(unsigned short* p, unsigned short v) {
    asm volatile("global_store_short %0, %1, off sc0 sc1" :: "v"(p), "v"((unsigned)v) : "memory");
}

// ---------------- maxlen: 1 + max t with any x[b,t] > 0 ----------------
__global__ void maxlen_kernel(const int* __restrict__ x, int* __restrict__ out) {
    __shared__ int mx;
    int t = threadIdx.x;          // 512 threads
    if (t == 0) mx = 1;
    __syncthreads();
    int any = 0;
    for (int b = 0; b < BB; ++b) any |= (x[b * TT + t] > 0);
    if (any) atomicMax(&mx, t + 1);
    __syncthreads();
    if (t == 0) out[0] = mx;
}

// ------- sentinel fill via agent-scope atomic stores; also zeroes tile counters ----
__global__ void sentfill_kernel(unsigned long long* __restrict__ p, int n,
                                int* __restrict__ cnt) {
    int i = blockIdx.x * 256 + threadIdx.x;
    if (i < n)
        __hip_atomic_store(p + i, SENT64, __ATOMIC_RELAXED, __HIP_MEMORY_SCOPE_AGENT);
    if (cnt && blockIdx.x == 0 && threadIdx.x < 128)
        __hip_atomic_store(cnt + threadIdx.x, 0, __ATOMIC_RELAXED, __HIP_MEMORY_SCOPE_AGENT);
}

// ---------------- embedding gather -> bf16 XS (T*B, 128) zero-padded ----------------
__global__ void embed_kernel(const int* __restrict__ x, const float* __restrict__ EW,
                             unsigned short* __restrict__ XS) {
    int idx = blockIdx.x * 256 + threadIdx.x;    // < 8192*128
    int e = idx & 127;
    int r = idx >> 7;          // r = t*16 + b
    int t = r >> 4;
    int b = r & 15;
    unsigned short v = 0;
    if (e < EE) {
        int tok = x[b * TT + t];
        v = (unsigned short)f2bf(EW[(size_t)tok * EE + e]);
    }
    XS[idx] = v;
}

// ---------------- fp32 -> bf16 weight conversion with K padding ----------------
__global__ void wconv_kernel(const float* __restrict__ src, unsigned short* __restrict__ dst,
                             int Ksrc, int Kpad, int total) {
    int i = blockIdx.x * 256 + threadIdx.x;
    if (i >= total) return;
    int r = i / Kpad;
    int k = i - r * Kpad;
    dst[i] = (k < Ksrc) ? (unsigned short)f2bf(src[(size_t)r * Ksrc + k]) : 0;
}

// ---------------- zero the pad columns (1000..1023) of bf16 H0 ----------------
__global__ void padzero_kernel(int* __restrict__ p) {
    int i = blockIdx.x * 256 + threadIdx.x;      // < 8192*12
    if (i >= 8192 * 12) return;
    int r = i / 12, c = i - r * 12;
    p[r * 512 + 500 + c] = 0;                    // shorts 1000..1023 = ints 500..511
}

// ------------- bf16 MFMA GEMM body: C[z] = f16(A @ W[z]^T + b1[z] + b2[z]) ---------
// A: (8192, Kpad) bf16. W: (2, 2000, Kpad) bf16. C: (2, 8192, 2000) fp16.
// Software-pipelined global loads (r4-verified). gcnt==nullptr: plain cached stores
// (standalone dispatch). gcnt!=nullptr (fused producer): write-through sc0sc1 stores,
// vmcnt drain, then release counter[z*64+bx] via agent atomic -> consumer-visible.
__device__ __forceinline__ void gemm_body(
    const unsigned short* __restrict__ A, const unsigned short* __restrict__ W,
    const float* __restrict__ b1, const float* __restrict__ b2,
    unsigned short* __restrict__ C, int Kpad, int bx, int by, int z,
    int* gcnt) {
    __shared__ __align__(16) unsigned short AsS[128 * 40];
    __shared__ __align__(16) unsigned short WsS[64 * 40];
    const int tid = threadIdx.x;
    const int lane = tid & 63;
    const int w = tid >> 6;
    const int quad = lane >> 4;
    const int nl = lane & 15;
    const int bm0 = bx * 128;
    const int n0 = by * 64;

    const unsigned short* Wz = W + (size_t)z * 2000 * Kpad;
    unsigned short* Cz = C + (size_t)z * 8192 * 2000;
    const float* b1z = b1 + (size_t)z * 2000;
    const float* b2z = b2 + (size_t)z * 2000;

    f32x4 acc[2][4];
#pragma unroll
    for (int mt = 0; mt < 2; ++mt)
#pragma unroll
        for (int nt = 0; nt < 4; ++nt) acc[mt][nt] = (f32x4){0.f, 0.f, 0.f, 0.f};

    const int arow = tid >> 2;
    const int kc = tid & 3;
    const int wn = n0 + arow;
    const bool wok = (wn < 2000);

    const unsigned short* Ap0 = A + (size_t)(bm0 + arow) * Kpad + kc * 8;
    const unsigned short* Ap1 = A + (size_t)(bm0 + 64 + arow) * Kpad + kc * 8;
    const unsigned short* Wp  = Wz + (size_t)(wok ? wn : 0) * Kpad + kc * 8;

    // preload tile 0
    short8 av0 = *(const short8*)(Ap0);
    short8 av1 = *(const short8*)(Ap1);
    short8 wv = {0, 0, 0, 0, 0, 0, 0, 0};
    if (wok) wv = *(const short8*)(Wp);

    for (int k0 = 0; k0 < Kpad; k0 += 32) {
        __syncthreads();           // prior iteration's fragment reads done (WAR)
        *(short8*)&AsS[arow * 40 + kc * 8] = av0;
        *(short8*)&AsS[(64 + arow) * 40 + kc * 8] = av1;
        *(short8*)&WsS[arow * 40 + kc * 8] = wv;
        __syncthreads();

        // issue next tile's loads now; latency hides under LDS reads + MFMA
        if (k0 + 32 < Kpad) {
            av0 = *(const short8*)(Ap0 + k0 + 32);
            av1 = *(const short8*)(Ap1 + k0 + 32);
            if (wok) wv = *(const short8*)(Wp + k0 + 32);
        }

        short8 af[2], bfr[4];
#pragma unroll
        for (int mt = 0; mt < 2; ++mt)
            af[mt] = *(const short8*)&AsS[(w * 32 + mt * 16 + nl) * 40 + quad * 8];
#pragma unroll
        for (int nt = 0; nt < 4; ++nt)
            bfr[nt] = *(const short8*)&WsS[(nt * 16 + nl) * 40 + quad * 8];
#pragma unroll
        for (int mt = 0; mt < 2; ++mt)
#pragma unroll
            for (int nt = 0; nt < 4; ++nt)
                acc[mt][nt] = __builtin_amdgcn_mfma_f32_16x16x32_bf16(
                    af[mt], bfr[nt], acc[mt][nt], 0, 0, 0);
    }

    if (!gcnt) {
#pragma unroll
        for (int nt = 0; nt < 4; ++nt) {
            int n = n0 + nt * 16 + nl;
            if (n < 2000) {
                float bb = b1z[n] + b2z[n];
#pragma unroll
                for (int mt = 0; mt < 2; ++mt) {
                    int mbase = bm0 + w * 32 + mt * 16 + quad * 4;
#pragma unroll
                    for (int reg = 0; reg < 4; ++reg)
                        Cz[(size_t)(mbase + reg) * 2000 + n] = f2h(acc[mt][nt][reg] + bb);
                }
            }
        }
    } else {
#pragma unroll
        for (int nt = 0; nt < 4; ++nt) {
            int n = n0 + nt * 16 + nl;
            if (n < 2000) {
                float bb = b1z[n] + b2z[n];
#pragma unroll
                for (int mt = 0; mt < 2; ++mt) {
                    int mbase = bm0 + w * 32 + mt * 16 + quad * 4;
#pragma unroll
                    for (int reg = 0; reg < 4; ++reg)
                        store_u16_wt(&Cz[(size_t)(mbase + reg) * 2000 + n],
                                     f2h(acc[mt][nt][reg] + bb));
                }
            }
        }
        // drain asm stores (compiler doesn't model them), then block-wide complete,
        // then release the tile counter (agent atomic -> MALL)
        asm volatile("s_waitcnt vmcnt(0)" ::: "memory");
        __syncthreads();
        if (tid == 0)
            __hip_atomic_fetch_add(&gcnt[z * 64 + bx], 1,
                                   __ATOMIC_RELAXED, __HIP_MEMORY_SCOPE_AGENT);
    }
}

__global__ __launch_bounds__(256) void gemm_mfma(
    const unsigned short* __restrict__ A, const unsigned short* __restrict__ W,
    const float* __restrict__ b1, const float* __restrict__ b2,
    unsigned short* __restrict__ C, int Kpad) {
    gemm_body(A, W, b1, b2, C, Kpad, blockIdx.x, blockIdx.y, blockIdx.z, nullptr);
}

// ---------------- persistent-weight recurrence, bf16 MFMA, DATA-IS-FLAG sync -------
// Core protocol identical to the proven baseline. Changes this round:
//  * G prefetch via sc0sc1 asm loads (coherent with fused write-through producer);
//    their completion is folded into the poll's vmcnt(0) via "+v" operands -> no
//    added latency (poll waits vmcnt(0) anyway).
//  * gcnt gating (fused layer-1 only): before prefetching G of a NEW 8-step row
//    tile, spin until counter[dir*64+tile] == 32 (all 32 column tiles stored).
//    Checked once per 8 steps -> ~75cy/step amortized. gcnt==nullptr: no gating.
//  * epilogue: fast sigmoid/tanh (r2-verified) + publish BEFORE Hout stores.
__device__ __forceinline__ void rec_body(
    const unsigned short* __restrict__ G, const float* __restrict__ Whh,
    const int* __restrict__ x, const float* __restrict__ h0,
    const float* __restrict__ c0, int layerbase,
    unsigned short* __restrict__ Hout, unsigned short* __restrict__ hseq,
    const int* __restrict__ mlen, int* gcnt, int blk)
{
    const int dir = blk >> 4;
    const int bsl = blk & 15;
    const int k0 = bsl * 32;
    const int tid = threadIdx.x;
    const int lane = tid & 63;
    const int w = tid >> 6;          // wave 0..3
    const int quad = lane >> 4;      // 0..3
    const int nl = lane & 15;
    const int L = mlen[0];           // 1..512

    const float* Wd = Whh + (size_t)dir * 2000 * HD;
    const unsigned short* Gd = G + (size_t)dir * TT * BB * 2000;
    unsigned short* hdir = hseq + (size_t)dir * (TT + 1) * 8192;

    __shared__ __align__(16) unsigned short hstage[8192];
    __shared__ float sg[4][32][17];

    // ---- load weights into registers as B fragments (bf16) ----
    short8 bf[2][16];
#pragma unroll
    for (int tl = 0; tl < 2; ++tl) {
        int tt = w * 2 + tl;
        int r = tt * 16 + nl;          // 0..127 local gate row
        int g = r >> 5;                // gate 0..3
        int lkr = r & 31;
        int kk = k0 + lkr;             // output h index
        const float* wrow = (kk < HD) ? (Wd + (size_t)(g * HD + kk) * HD) : (const float*)0;
#pragma unroll
        for (int ks = 0; ks < 16; ++ks) {
            int kg0 = ks * 32 + quad * 8;
            short8 v;
            if (wrow && kg0 + 8 <= HD) {
                float4 f0 = *(const float4*)(wrow + kg0);
                float4 f1 = *(const float4*)(wrow + kg0 + 4);
                v[0] = f2bf(f0.x); v[1] = f2bf(f0.y); v[2] = f2bf(f0.z); v[3] = f2bf(f0.w);
                v[4] = f2bf(f1.x); v[5] = f2bf(f1.y); v[6] = f2bf(f1.z); v[7] = f2bf(f1.w);
            } else {
#pragma unroll
                for (int j = 0; j < 8; ++j) {
                    int kg = kg0 + j;
                    float f = (wrow && kg < HD) ? wrow[kg] : 0.f;
                    v[j] = f2bf(f);
                }
            }
            bf[tl][ks] = v;
        }
    }

    // ---- per-thread persistent state: 2 (b,k) pairs, same k different b ----
    const int lk = tid & 31;
    const int k  = k0 + lk;
    const bool kok = (k < HD);
    const int b0v = tid >> 5;          // 0..7
    const int b1v = 8 + (tid >> 5);    // 8..15
    float h_st[2] = {0.f, 0.f}, c_st[2] = {0.f, 0.f};
    if (kok) {
        size_t base0 = (size_t)(layerbase + dir) * BB * HD + (size_t)b0v * HD + k;
        size_t base1 = (size_t)(layerbase + dir) * BB * HD + (size_t)b1v * HD + k;
        h_st[0] = h0[base0]; c_st[0] = c0[base0];
        h_st[1] = h0[base1]; c_st[1] = c0[base1];
    }

    // ---- publish h0 into buf[0] (ALL slots: zeros for k>=HD; 8B atomic stores) ----
    {
        int i0 = (int)(unsigned short)f2bf(kok ? h_st[0] : 0.f);
        int i1 = (int)(unsigned short)f2bf(kok ? h_st[1] : 0.f);
        int a0 = __shfl_down(i0, 1), c0s = __shfl_down(i0, 2), d0 = __shfl_down(i0, 3);
        int a1 = __shfl_down(i1, 1), c1s = __shfl_down(i1, 2), d1 = __shfl_down(i1, 3);
        if ((lk & 3) == 0) {
            unsigned long long p0 = (unsigned long long)(unsigned)(i0 | (a0 << 16))
                                  | ((unsigned long long)(unsigned)(c0s | (d0 << 16)) << 32);
            unsigned long long p1 = (unsigned long long)(unsigned)(i1 | (a1 << 16))
                                  | ((unsigned long long)(unsigned)(c1s | (d1 << 16)) << 32);
            int idx0 = bsl * 512 + (b0v + 16 * (lk >> 3)) * 8 + (lk & 7);
            int idx1 = bsl * 512 + (b1v + 16 * (lk >> 3)) * 8 + (lk & 7);
            __hip_atomic_store((unsigned long long*)(hdir + idx0), p0,
                               __ATOMIC_RELAXED, __HIP_MEMORY_SCOPE_AGENT);
            __hip_atomic_store((unsigned long long*)(hdir + idx1), p1,
                               __ATOMIC_RELAXED, __HIP_MEMORY_SCOPE_AGENT);
        }
    }

    // ---- G prefetch state: 8 raw ushorts in asm-managed regs + masks ----
    unsigned g00 = 0, g01 = 0, g02 = 0, g03 = 0, g10 = 0, g11 = 0, g12 = 0, g13 = 0;
    int m[2]; m[0] = m[1] = 0;
    int lastTile = -1;

    // ---- step-0 gate + prefetch (loads left in flight; poll's vmcnt(0) covers) ----
    {
        int t = dir ? (L - 1) : 0;
        if (gcnt) {
            int tile = dir * 64 + (t >> 3);
            while (__hip_atomic_load(&gcnt[tile], __ATOMIC_RELAXED,
                                     __HIP_MEMORY_SCOPE_AGENT) < 32) {}
            lastTile = tile;
        }
        if (kok) {
            const unsigned short* gr0 = Gd + ((size_t)t * BB + b0v) * 2000 + k;
            const unsigned short* gr1 = Gd + ((size_t)t * BB + b1v) * 2000 + k;
            asm volatile(
                "global_load_ushort %0, %8, off sc0 sc1\n\t"
                "global_load_ushort %1, %8, off offset:1000 sc0 sc1\n\t"
                "global_load_ushort %2, %8, off offset:2000 sc0 sc1\n\t"
                "global_load_ushort %3, %8, off offset:3000 sc0 sc1\n\t"
                "global_load_ushort %4, %9, off sc0 sc1\n\t"
                "global_load_ushort %5, %9, off offset:1000 sc0 sc1\n\t"
                "global_load_ushort %6, %9, off offset:2000 sc0 sc1\n\t"
                "global_load_ushort %7, %9, off offset:3000 sc0 sc1"
                : "=&v"(g00), "=&v"(g01), "=&v"(g02), "=&v"(g03),
                  "=&v"(g10), "=&v"(g11), "=&v"(g12), "=&v"(g13)
                : "v"(gr0), "v"(gr1) : "memory");
            m[0] = x[b0v * TT + t] > 0;
            m[1] = x[b1v * TT + t] > 0;
        }
    }

    for (int s = 0; s < L; ++s) {
        const int t = dir ? (L - 1 - s) : s;
        const unsigned short* bufr = hdir + (size_t)s * 8192;
        unsigned short* bufw = hdir + (size_t)(s + 1) * 8192;

        // ---- poll-stage buf[s] into LDS: per-thread 4x16B sc0/sc1 loads, retry
        //      until no 4B word is the sentinel. The in-flight G loads ride through
        //      as "+v" operands: vmcnt(0) completes them -> valid after this asm ----
        {
            const unsigned short* p0 = bufr + (tid +   0) * 8;
            const unsigned short* p1 = bufr + (tid + 256) * 8;
            const unsigned short* p2 = bufr + (tid + 512) * 8;
            const unsigned short* p3 = bufr + (tid + 768) * 8;
            u32x4 c0v, c1v, c2v, c3v;
            for (;;) {
                asm volatile(
                    "global_load_dwordx4 %0, %12, off sc0 sc1\n\t"
                    "global_load_dwordx4 %1, %13, off sc0 sc1\n\t"
                    "global_load_dwordx4 %2, %14, off sc0 sc1\n\t"
                    "global_load_dwordx4 %3, %15, off sc0 sc1\n\t"
                    "s_waitcnt vmcnt(0)"
                    : "=&v"(c0v), "=&v"(c1v), "=&v"(c2v), "=&v"(c3v),
                      "+v"(g00), "+v"(g01), "+v"(g02), "+v"(g03),
                      "+v"(g10), "+v"(g11), "+v"(g12), "+v"(g13)
                    : "v"(p0), "v"(p1), "v"(p2), "v"(p3)
                    : "memory");
                unsigned bad = 0;
#pragma unroll
                for (int q = 0; q < 4; ++q)
                    bad |= (c0v[q] == SENT32) | (c1v[q] == SENT32)
                         | (c2v[q] == SENT32) | (c3v[q] == SENT32);
                if (!bad) break;
            }
            *(u32x4*)&hstage[(tid +   0) * 8] = c0v;
            *(u32x4*)&hstage[(tid + 256) * 8] = c1v;
            *(u32x4*)&hstage[(tid + 512) * 8] = c2v;
            *(u32x4*)&hstage[(tid + 768) * 8] = c3v;
        }
        __syncthreads();

        // ---- recurrent preactivation via MFMA (A fragments from LDS) ----
        f32x4 acc0 = {0.f, 0.f, 0.f, 0.f};
        f32x4 acc1 = {0.f, 0.f, 0.f, 0.f};
#pragma unroll
        for (int ks = 0; ks < 16; ++ks) {
            short8 a = *(const short8*)&hstage[ks * 512 + lane * 8];
            acc0 = __builtin_amdgcn_mfma_f32_16x16x32_bf16(a, bf[0][ks], acc0, 0, 0, 0);
            acc1 = __builtin_amdgcn_mfma_f32_16x16x32_bf16(a, bf[1][ks], acc1, 0, 0, 0);
        }

        // ---- scatter D to LDS: sg[gate][lk][b] ----
        {
            int r0 = (w * 2 + 0) * 16 + nl;
            int r1 = (w * 2 + 1) * 16 + nl;
            int g0r = r0 >> 5, lk0 = r0 & 31;
            int g1r = r1 >> 5, lk1 = r1 & 31;
#pragma unroll
            for (int reg = 0; reg < 4; ++reg) {
                int b = quad * 4 + reg;
                sg[g0r][lk0][b] = acc0[reg];
                sg[g1r][lk1][b] = acc1[reg];
            }
        }
        __syncthreads();

        // ---- epilogue: gates + state update (fast transcendentals), publish ASAP,
        //      then Hout (off the peers' critical path) ----
        int i0 = 0, i1 = 0;
        if (kok) {
            {
                float si  = sg[0][lk][b0v] + h2f((unsigned short)g00);
                float sf  = sg[1][lk][b0v] + h2f((unsigned short)g01);
                float sgg = sg[2][lk][b0v] + h2f((unsigned short)g02);
                float so  = sg[3][lk][b0v] + h2f((unsigned short)g03);
                float c_new = sigm_fast(sf) * c_st[0] + sigm_fast(si) * tanh_fast(sgg);
                float h_new = sigm_fast(so) * tanh_fast(c_new);
                if (m[0]) { h_st[0] = h_new; c_st[0] = c_new; }
            }
            {
                float si  = sg[0][lk][b1v] + h2f((unsigned short)g10);
                float sf  = sg[1][lk][b1v] + h2f((unsigned short)g11);
                float sgg = sg[2][lk][b1v] + h2f((unsigned short)g12);
                float so  = sg[3][lk][b1v] + h2f((unsigned short)g13);
                float c_new = sigm_fast(sf) * c_st[1] + sigm_fast(si) * tanh_fast(sgg);
                float h_new = sigm_fast(so) * tanh_fast(c_new);
                if (m[1]) { h_st[1] = h_new; c_st[1] = c_new; }
            }
            i0 = (int)(unsigned short)f2bf(h_st[0]);
            i1 = (int)(unsigned short)f2bf(h_st[1]);
        }

        // ---- publish h into buf[s+1] (ALL slots; 8B atomic stores; no barrier) ----
        {
            int a0 = __shfl_down(i0, 1), c0s = __shfl_down(i0, 2), d0 = __shfl_down(i0, 3);
            int a1 = __shfl_down(i1, 1), c1s = __shfl_down(i1, 2), d1 = __shfl_down(i1, 3);
            if ((lk & 3) == 0) {
                unsigned long long p0 = (unsigned long long)(unsigned)(i0 | (a0 << 16))
                                      | ((unsigned long long)(unsigned)(c0s | (d0 << 16)) << 32);
                unsigned long long p1 = (unsigned long long)(unsigned)(i1 | (a1 << 16))
                                      | ((unsigned long long)(unsigned)(c1s | (d1 << 16)) << 32);
                int idx0 = bsl * 512 + (b0v + 16 * (lk >> 3)) * 8 + (lk & 7);
                int idx1 = bsl * 512 + (b1v + 16 * (lk >> 3)) * 8 + (lk & 7);
                __hip_atomic_store((unsigned long long*)(bufw + idx0), p0,
                                   __ATOMIC_RELAXED, __HIP_MEMORY_SCOPE_AGENT);
                __hip_atomic_store((unsigned long long*)(bufw + idx1), p1,
                                   __ATOMIC_RELAXED, __HIP_MEMORY_SCOPE_AGENT);
            }
        }

        // ---- Hout (bf16, stride 1024): same bits as published; after publish ----
        if (kok) {
            Hout[((size_t)t * BB + b0v) * 1024 + dir * HD + k] =
                (unsigned short)(m[0] ? i0 : 0);
            Hout[((size_t)t * BB + b1v) * 1024 + dir * HD + k] =
                (unsigned short)(m[1] ? i1 : 0);
        }

        // ---- prefetch next step's G (gated per row-tile) + mask ----
        if (s + 1 < L) {
            int tn = dir ? (L - 2 - s) : (s + 1);
            if (gcnt) {
                int tile = dir * 64 + (tn >> 3);
                if (tile != lastTile) {
                    while (__hip_atomic_load(&gcnt[tile], __ATOMIC_RELAXED,
                                             __HIP_MEMORY_SCOPE_AGENT) < 32) {}
                    lastTile = tile;
                }
            }
            if (kok) {
                const unsigned short* gr0 = Gd + ((size_t)tn * BB + b0v) * 2000 + k;
                const unsigned short* gr1 = Gd + ((size_t)tn * BB + b1v) * 2000 + k;
                asm volatile(
                    "global_load_ushort %0, %8, off sc0 sc1\n\t"
                    "global_load_ushort %1, %8, off offset:1000 sc0 sc1\n\t"
                    "global_load_ushort %2, %8, off offset:2000 sc0 sc1\n\t"
                    "global_load_ushort %3, %8, off offset:3000 sc0 sc1\n\t"
                    "global_load_ushort %4, %9, off sc0 sc1\n\t"
                    "global_load_ushort %5, %9, off offset:1000 sc0 sc1\n\t"
                    "global_load_ushort %6, %9, off offset:2000 sc0 sc1\n\t"
                    "global_load_ushort %7, %9, off offset:3000 sc0 sc1"
                    : "=&v"(g00), "=&v"(g01), "=&v"(g02), "=&v"(g03),
                      "=&v"(g10), "=&v"(g11), "=&v"(g12), "=&v"(g13)
                    : "v"(gr0), "v"(gr1) : "memory");
                m[0] = x[b0v * TT + tn] > 0;
                m[1] = x[b1v * TT + tn] > 0;
            }
        }
    }
}

__global__ __launch_bounds__(256, 1) void rec10_kernel(
    const unsigned short* __restrict__ G, const float* __restrict__ Whh,
    const int* __restrict__ x, const float* __restrict__ h0,
    const float* __restrict__ c0, int layerbase,
    unsigned short* __restrict__ Hout, unsigned short* __restrict__ hseq,
    const int* __restrict__ mlen) {
    rec_body(G, Whh, x, h0, c0, layerbase, Hout, hseq, mlen, nullptr, blockIdx.x);
}

// -------- FUSED layer-1: blocks 0..31 = recurrence (counter-gated G); blocks
// 32..4127 = input-projection GEMM tiles releasing counters. Deadlock-free: gemm
// blocks never wait; rec blocks are first in dispatch order (32 CUs), gemm fills the
// remaining 224 and retires continuously. z=1 tiles processed in DESCENDING bx so the
// backward direction's high-t tiles are produced first. --------
__global__ __launch_bounds__(256, 1) void fused1_kernel(
    unsigned short* __restrict__ Gh, const float* __restrict__ Whh1,
    const int* __restrict__ x, const float* __restrict__ h0,
    const float* __restrict__ c0, unsigned short* __restrict__ HSb,
    unsigned short* __restrict__ hseq, const int* __restrict__ mlen,
    const unsigned short* __restrict__ H0b, const unsigned short* __restrict__ Wb1,
    const float* __restrict__ bih1, const float* __restrict__ bhh1,
    int* gcnt) {
    int bid = blockIdx.x;
    if (bid < 32) {
        rec_body(Gh, Whh1, x, h0, c0, 2, HSb, hseq, mlen, gcnt, bid);
    } else {
        int gx = bid - 32;          // 0..4095
        int z = gx & 1;
        int rem = gx >> 1;          // 0..2047
        int bx = rem >> 5;          // 0..63  (by varies fastest -> tiles complete in bx order)
        int by = rem & 31;          // 0..31
        if (z) bx = 63 - bx;        // backward dir: high-t tiles first
        gemm_body(H0b, Wb1, bih1, bhh1, Gh, 1024, bx, by, z, gcnt);
    }
}

// -------- output projection: Y (T,B,32) = bf16HS @ Wo^T + bo, masked ----------------
__global__ __launch_bounds__(256) void outproj_kernel(
    const unsigned short* __restrict__ HS, const float* __restrict__ Wo,
    const float* __restrict__ bo, const int* __restrict__ x,
    float* __restrict__ Y) {
    __shared__ float wlds[8 * 1000];
    const int bid = blockIdx.x;          // 1024 blocks
    const int tid = threadIdx.x;         // 256
    const int rblk = bid >> 2;           // 0..255
    const int n0 = (bid & 3) * 8;        // 0,8,16,24
    for (int i = tid; i < 8000; i += 256) {
        int nn = i / 1000;
        int q = i - nn * 1000;
        wlds[i] = Wo[(size_t)(n0 + nn) * 1000 + q];
    }
    __syncthreads();
    const int r = rblk * 32 + (tid >> 3);
    const int n = n0 + (tid & 7);
    const int t = r >> 4;
    const int b = r & 15;
    float out = 0.f;
    if (x[b * TT + t] > 0) {
        const unsigned short* h = HS + (size_t)r * 1024;
        const float* wrow = &wlds[(tid & 7) * 1000];
        float s = 0.f;
#pragma unroll 4
        for (int q = 0; q < 1000; q += 8) {
            short8 hv = *(const short8*)(h + q);
            float4 w0 = *(const float4*)(wrow + q);
            float4 w1 = *(const float4*)(wrow + q + 4);
            s += bf2f((unsigned short)hv[0]) * w0.x + bf2f((unsigned short)hv[1]) * w0.y
               + bf2f((unsigned short)hv[2]) * w0.z + bf2f((unsigned short)hv[3]) * w0.w
               + bf2f((unsigned short)hv[4]) * w1.x + bf2f((unsigned short)hv[5]) * w1.y
               + bf2f((unsigned short)hv[6]) * w1.z + bf2f((unsigned short)hv[7]) * w1.w;
        }
        out = s + bo[n];
    }
    Y[(size_t)r * 32 + n] = out;
}

// ---------------- CRF: gold score + forward scan (single-barrier, prefetched) ------
__global__ __launch_bounds__(1024) void crf_kernel(
    const float* __restrict__ Y, const int* __restrict__ x, const int* __restrict__ y0,
    const float* __restrict__ trans, float* __restrict__ out_pb) {
    int b = blockIdx.x;
    int tid = threadIdx.x;
    int i = tid >> 5;
    int j = tid & 31;
    float tr_ij = trans[i * 32 + j];

    __shared__ float scb[2][32];
    __shared__ float wred[16];
    __shared__ float goldS;

    float gp = 0.f;
    if (tid < TT) {
        int t = tid;
        int xm = x[b * TT + t];
        float mf = (xm > 0) ? 1.f : 0.f;
        int ynext = y0[b * TT + t];
        int yprev = (t == 0) ? 1 : y0[b * TT + t - 1];
        gp = Y[((size_t)t * BB + b) * 32 + ynext] + trans[ynext * 32 + yprev] * mf;
    }
#pragma unroll
    for (int d = 32; d >= 1; d >>= 1) gp += __shfl_down(gp, d);
    if ((tid & 63) == 0) wred[tid >> 6] = gp;
    __syncthreads();
    if (tid == 0) {
        float s = 0.f;
        for (int ww = 0; ww < 16; ++ww) s += wred[ww];
        goldS = s;
    }
    if (tid < 32) scb[0][tid] = (tid == 1) ? 0.f : NEG;
    __syncthreads();

    int cur = 0;
    float emit_c = Y[((size_t)0 * BB + b) * 32 + i];
    int mm_c = x[b * TT + 0] > 0;
    for (int t = 0; t < TT; ++t) {
        float emit_n = 0.f;
        int mm_n = 0;
        if (t + 1 < TT) {
            emit_n = Y[((size_t)(t + 1) * BB + b) * 32 + i];
            mm_n = x[b * TT + t + 1] > 0;
        }
        float sj = scb[cur][j];
        float z = sj + tr_ij;
        float mx = z;
#pragma unroll
        for (int d = 16; d >= 1; d >>= 1) mx = fmaxf(mx, __shfl_xor(mx, d));
        float e = __expf(z - mx);
#pragma unroll
        for (int d = 16; d >= 1; d >>= 1) e += __shfl_xor(e, d);
        float cm = sj;
#pragma unroll
        for (int d = 16; d >= 1; d >>= 1) cm = fmaxf(cm, __shfl_xor(cm, d));
        float newv = emit_c + mx + __logf(e);
        if (j == 0) scb[cur ^ 1][i] = mm_c ? newv : cm;
        __syncthreads();
        cur ^= 1;
        emit_c = emit_n;
        mm_c = mm_n;
    }

    if (tid < 32) {
        float v = scb[cur][tid];
        float mx = v;
#pragma unroll
        for (int d = 16; d >= 1; d >>= 1) mx = fmaxf(mx, __shfl_xor(mx, d));
        float e = __expf(v - mx);
#pragma unroll
        for (int d = 16; d >= 1; d >>= 1) e += __shfl_xor(e, d);
        if (tid == 0) out_pb[b] = (mx + __logf(e)) - goldS;
    }
}

__global__ void final_kernel(const float* __restrict__ out_pb, float* __restrict__ out) {
    if (threadIdx.x == 0 && blockIdx.x == 0) {
        float s = 0.f;
        for (int b = 0; b < BB; ++b) s += out_pb[b];
        out[0] = s / (float)BB;
    }
}

extern "C" void kernel_launch(void* const* d_in, const int* in_sizes, int n_in,
                              void* d_out, int out_size, void* d_ws, size_t ws_size,
                              hipStream_t stream) {
    const int*   x     = (const int*)d_in[0];
    const int*   y0    = (const int*)d_in[1];
    const float* EW    = (const float*)d_in[2];
    const float* Wih0  = (const float*)d_in[3];
    const float* Whh0  = (const float*)d_in[4];
    const float* bih0  = (const float*)d_in[5];
    const float* bhh0  = (const float*)d_in[6];
    const float* Wih1  = (const float*)d_in[7];
    const float* Whh1  = (const float*)d_in[8];
    const float* bih1  = (const float*)d_in[9];
    const float* bhh1  = (const float*)d_in[10];
    const float* Wo    = (const float*)d_in[11];
    const float* bo    = (const float*)d_in[12];
    const float* trans = (const float*)d_in[13];
    const float* h0    = (const float*)d_in[14];
    const float* c0    = (const float*)d_in[15];

    float* ws = (float*)d_ws;
    // Layout (float offsets), total 31,803,521 floats = 127.2 MB:
    //   [0, 524288)            XS bf16 (8192x128); Y fp32(262144)+crfbuf alias
    //   [524288, 16908288)     Gh: fp16 (2, 8192, 2000)
    //   [16908288, 21102592)   H0 bf16 (8192 x 1024)
    //   [21102592, 25296896)   HS bf16 (8192 x 1024)
    //   [25296896, 25552896)   Wb0 bf16 (2,2000,128)
    //   [25552896, 27600896)   Wb1 bf16 (2,2000,1024)
    //   [27600896, 31803392)   hseq: 2 dirs x 513 x 8192 bf16 (shared by both layers)
    //   [31803392]             mlen (1 int)
    //   [31803393, 31803521)   gcnt: tile counters (2 dirs x 64 row-tiles)
    unsigned short* XS = (unsigned short*)ws;
    float* Y      = ws;
    float* crfbuf = ws + 262144;
    unsigned short* Gh   = (unsigned short*)(ws + 524288);
    unsigned short* H0b  = (unsigned short*)(ws + 16908288);
    unsigned short* HSb  = (unsigned short*)(ws + 21102592);
    unsigned short* Wb0  = (unsigned short*)(ws + 25296896);
    unsigned short* Wb1  = (unsigned short*)(ws + 25552896);
    unsigned short* hseq = (unsigned short*)(ws + 27600896);
    int* mlen     = (int*)(ws + 31803392);
    int* gcnt     = (int*)(ws + 31803393);
    const int nsent64 = 2 * (TT + 1) * 8192 / 4;   // 2,101,248 u64 words

    // Phase 0: maxlen + sentinel fill #1 (also zeroes counters)
    maxlen_kernel<<<1, 512, 0, stream>>>(x, mlen);
    sentfill_kernel<<<(nsent64 + 255) / 256, 256, 0, stream>>>((unsigned long long*)hseq, nsent64, gcnt);

    // Phase 1: embedding -> bf16 XS (padded K=128); weight conversions
    embed_kernel<<<4096, 256, 0, stream>>>(x, EW, XS);
    wconv_kernel<<<(512000 + 255) / 256, 256, 0, stream>>>(Wih0, Wb0, 100, 128, 512000);
    wconv_kernel<<<(4096000 + 255) / 256, 256, 0, stream>>>(Wih1, Wb1, 1000, 1024, 4096000);

    // Phase 2: layer-0 input projections (MFMA, Kpad=128) -> fp16 Gh; zero H0 pads
    gemm_mfma<<<dim3(64, 32, 2), 256, 0, stream>>>(XS, Wb0, bih0, bhh0, Gh, 128);
    padzero_kernel<<<(98304 + 255) / 256, 256, 0, stream>>>((int*)H0b);

    // Phase 3: layer-0 recurrence -> bf16 H0 (data-is-flag; fast-math epilogue)
    rec10_kernel<<<32, 256, 0, stream>>>(Gh, Whh0, x, h0, c0, 0, H0b, hseq, mlen);

    // Phase 4: refill hseq sentinels + zero tile counters
    sentfill_kernel<<<(nsent64 + 255) / 256, 256, 0, stream>>>((unsigned long long*)hseq, nsent64, gcnt);

    // Phase 5: FUSED layer-1 GEMM + recurrence -> bf16 HS
    fused1_kernel<<<32 + 4096, 256, 0, stream>>>(Gh, Whh1, x, h0, c0, HSb, hseq, mlen,
                                                 H0b, Wb1, bih1, bhh1, gcnt);

    // Phase 6: output projection (masked; bf16 HS, stride 1024; Wo staged in LDS)
    outproj_kernel<<<1024, 256, 0, stream>>>(HSb, Wo, bo, x, Y);

    // Phase 7: CRF gold + forward scan
    crf_kernel<<<BB, 1024, 0, stream>>>(Y, x, y0, trans, crfbuf);

    // Phase 8: mean
    final_kernel<<<1, 64, 0, stream>>>(crfbuf, (float*)d_out);
}